// Round 2
// baseline (12672.321 us; speedup 1.0000x reference)
//
#include <hip/hip_runtime.h>
#include <cmath>

#define S_LEN 2048
#define NTOK  8192   // B*S
#define TOPK  35

// ---------------- embedding + sinusoidal PE ----------------
// h[t][c] = sum_k x[t][k]*W[k][c] + b[c] + pe(s, c)
__global__ void embed_kernel(const float* __restrict__ x, const float* __restrict__ w,
                             const float* __restrict__ bias, float* __restrict__ h){
  int t = blockIdx.x;          // token 0..8191
  int tid = threadIdx.x;       // 0..255
  __shared__ float xs[64];
  if (tid < 64) xs[tid] = x[(size_t)t*64 + tid];
  __syncthreads();
  float acc0 = bias[tid];
  float acc1 = bias[tid + 256];
  #pragma unroll 8
  for (int k = 0; k < 64; ++k){
    float xv = xs[k];
    acc0 += xv * w[k*512 + tid];
    acc1 += xv * w[k*512 + tid + 256];
  }
  int s = t & (S_LEN - 1);
  const float neg_ln1e4_over_D = -9.210340371976184f / 512.f;
  int c0 = tid, c1 = tid + 256;
  float a0 = (float)s * expf((float)(c0 & ~1) * neg_ln1e4_over_D);
  float p0 = (c0 & 1) ? cosf(a0) : sinf(a0);
  float a1 = (float)s * expf((float)(c1 & ~1) * neg_ln1e4_over_D);
  float p1 = (c1 & 1) ? cosf(a1) : sinf(a1);
  h[(size_t)t*512 + c0] = acc0 + p0;
  h[(size_t)t*512 + c1] = acc1 + p1;
}

// ---------------- generic fp32 GEMM: C = A[M,K] @ W[K,N] + bias ----------------
// MODE 0: plain, MODE 1: relu, MODE 2: scatter to [B,H,S,DK] layout (N must be 512)
template<int MODE>
__global__ void gemm_f32(const float* __restrict__ A, const float* __restrict__ W,
                         const float* __restrict__ bias, float* __restrict__ C,
                         int M, int N, int K){
  __shared__ __align__(16) float As[16][64];
  __shared__ __align__(16) float Ws[16][64];
  int tx = threadIdx.x, ty = threadIdx.y;     // 16x16
  int tid = ty*16 + tx;
  int m0 = blockIdx.y * 64, n0 = blockIdx.x * 64;
  float acc[4][4];
  #pragma unroll
  for (int i = 0; i < 4; ++i)
    #pragma unroll
    for (int j = 0; j < 4; ++j) acc[i][j] = 0.f;

  int lm = tid >> 2;          // 0..63 (A row within tile)
  int lk = (tid & 3) * 4;     // 0,4,8,12
  int wk = tid >> 4;          // 0..15 (W k within tile)
  int wn = (tid & 15) * 4;    // 0..60

  for (int k0 = 0; k0 < K; k0 += 16){
    float4 av = *(const float4*)(A + (size_t)(m0 + lm)*K + k0 + lk);
    As[lk+0][lm] = av.x; As[lk+1][lm] = av.y; As[lk+2][lm] = av.z; As[lk+3][lm] = av.w;
    float4 wv = *(const float4*)(W + (size_t)(k0 + wk)*N + n0 + wn);
    Ws[wk][wn+0] = wv.x; Ws[wk][wn+1] = wv.y;
    Ws[wk][wn+2] = wv.z; Ws[wk][wn+3] = wv.w;
    __syncthreads();
    #pragma unroll
    for (int k = 0; k < 16; ++k){
      float4 a = *(const float4*)&As[k][ty*4];
      float4 b = *(const float4*)&Ws[k][tx*4];
      float ar[4] = {a.x, a.y, a.z, a.w};
      float br[4] = {b.x, b.y, b.z, b.w};
      #pragma unroll
      for (int i = 0; i < 4; ++i)
        #pragma unroll
        for (int j = 0; j < 4; ++j) acc[i][j] += ar[i]*br[j];
    }
    __syncthreads();
  }

  #pragma unroll
  for (int i = 0; i < 4; ++i){
    int row = m0 + ty*4 + i;
    #pragma unroll
    for (int j = 0; j < 4; ++j){
      int col = n0 + tx*4 + j;
      float v = acc[i][j] + bias[col];
      if (MODE == 1) v = fmaxf(v, 0.f);
      if (MODE == 2){
        int b = row >> 11, s = row & 2047;    // S=2048
        int hh = col >> 6, d = col & 63;      // DK=64
        C[(((size_t)(b*8 + hh))*2048 + s)*64 + d] = v;
      } else {
        C[(size_t)row*N + col] = v;
      }
    }
  }
}

// ---------------- fused scores + top-35 + softmax + P@V[:35] ----------------
// One wave per query row. q/k/v in [B*H, S, 64] layout. ao written [B,S,H*64].
__global__ __launch_bounds__(256) void attn_topk_kernel(
    const float* __restrict__ qb, const float* __restrict__ kb,
    const float* __restrict__ vb, float* __restrict__ aob){
  int wid  = threadIdx.x >> 6;
  int lane = threadIdx.x & 63;
  int R  = blockIdx.x * 4 + wid;     // 0..65535
  int bh = R >> 11;                  // b*H + h
  int s  = R & 2047;
  __shared__ __align__(16) float qs[4][64];
  __shared__ float topv[4][TOPK];
  qs[wid][lane] = qb[(size_t)R*64 + lane];
  __syncthreads();
  float4 qreg[16];
  const float4* q4 = (const float4*)qs[wid];
  #pragma unroll
  for (int d = 0; d < 16; ++d) qreg[d] = q4[d];

  // scores: lane owns key rows j = it*64 + lane, it = 0..31
  const float* Kb = kb + (size_t)bh * (2048*64);
  float sc[32];
  #pragma unroll
  for (int it = 0; it < 32; ++it){
    const float4* k4 = (const float4*)(Kb + (size_t)(it*64 + lane)*64);
    float a = 0.f;
    #pragma unroll
    for (int d = 0; d < 16; ++d){
      float4 kk = k4[d];
      a += qreg[d].x*kk.x + qreg[d].y*kk.y + qreg[d].z*kk.z + qreg[d].w*kk.w;
    }
    sc[it] = a * 0.125f;   // 1/sqrt(64)
  }

  // iterative top-35 (descending); ties order-invariant for the output
  for (int r = 0; r < TOPK; ++r){
    float best = -INFINITY; int bslot = -1;
    #pragma unroll
    for (int j = 0; j < 32; ++j){ if (sc[j] > best){ best = sc[j]; bslot = j; } }
    float m = best;
    #pragma unroll
    for (int off = 32; off > 0; off >>= 1) m = fmaxf(m, __shfl_xor(m, off, 64));
    unsigned long long msk = __ballot(best == m);
    int owner = __ffsll(msk) - 1;
    if (lane == owner){
      #pragma unroll
      for (int j = 0; j < 32; ++j) if (j == bslot) sc[j] = -INFINITY;
    }
    if (lane == 0) topv[wid][r] = m;
  }
  __syncthreads();

  // softmax over the 35 sorted values; weight r pairs with V row r (reference quirk)
  float mx = topv[wid][0];
  float w[TOPK];
  float denom = 0.f;
  #pragma unroll
  for (int r = 0; r < TOPK; ++r){ w[r] = expf(topv[wid][r] - mx); denom += w[r]; }
  float inv = 1.f / denom;
  const float* Vb = vb + (size_t)bh * (2048*64) + lane;   // lane = d
  float acc = 0.f;
  #pragma unroll
  for (int r = 0; r < TOPK; ++r) acc += w[r] * Vb[(size_t)r*64];
  acc *= inv;
  int b = bh >> 3, hh = bh & 7;
  aob[(((size_t)(b*2048 + s))*8 + hh)*64 + lane] = acc;
}

// ---------------- h = LayerNorm(h + t) * g + b, in place ----------------
__global__ void resid_ln_kernel(float* __restrict__ h, const float* __restrict__ t,
                                const float* __restrict__ g, const float* __restrict__ b){
  int tok = blockIdx.x;
  int tid = threadIdx.x;        // 256 threads, 2 elems each
  size_t base = (size_t)tok * 512;
  float x0 = h[base + tid]       + t[base + tid];
  float x1 = h[base + tid + 256] + t[base + tid + 256];
  __shared__ float red[8];
  int wid = tid >> 6, lane = tid & 63;

  float s = x0 + x1;
  #pragma unroll
  for (int off = 32; off > 0; off >>= 1) s += __shfl_xor(s, off, 64);
  if (lane == 0) red[wid] = s;
  __syncthreads();
  float mean = (red[0] + red[1] + red[2] + red[3]) * (1.f/512.f);

  float d0 = x0 - mean, d1 = x1 - mean;
  float sq = d0*d0 + d1*d1;
  #pragma unroll
  for (int off = 32; off > 0; off >>= 1) sq += __shfl_xor(sq, off, 64);
  if (lane == 0) red[4 + wid] = sq;
  __syncthreads();
  float var = (red[4] + red[5] + red[6] + red[7]) * (1.f/512.f);
  float inv = rsqrtf(var + 1e-5f);
  h[base + tid]       = d0 * inv * g[tid]       + b[tid];
  h[base + tid + 256] = d1 * inv * g[tid + 256] + b[tid + 256];
}

// ---------------- mean over sequence ----------------
__global__ void pool_kernel(const float* __restrict__ h, float* __restrict__ pooled){
  int c = blockIdx.x * 256 + threadIdx.x;   // 0..511
  int b = blockIdx.y;
  const float* p = h + (size_t)b * 2048 * 512 + c;
  float acc = 0.f;
  for (int s = 0; s < 2048; ++s) acc += p[(size_t)s * 512];
  pooled[b*512 + c] = acc * (1.f/2048.f);
}

// ---------------- tiny decoder: relu(pooled@W1+b1)@W2+b2 -> out [4,2] ----------------
__global__ void decoder_kernel(const float* __restrict__ pooled,
                               const float* __restrict__ w1, const float* __restrict__ b1,
                               const float* __restrict__ w2, const float* __restrict__ b2,
                               float* __restrict__ out){
  __shared__ float ps[4][512];
  __shared__ float hid[4][256];
  int tid = threadIdx.x;
  for (int i = tid; i < 2048; i += 256) ps[i >> 9][i & 511] = pooled[i];
  __syncthreads();
  float bb = b1[tid];
  for (int b = 0; b < 4; ++b){
    float acc = bb;
    for (int k = 0; k < 512; ++k) acc += ps[b][k] * w1[k*256 + tid];
    hid[b][tid] = fmaxf(acc, 0.f);
  }
  __syncthreads();
  if (tid < 8){
    int b = tid >> 1, c = tid & 1;
    float acc = b2[c];
    for (int j = 0; j < 256; ++j) acc += hid[b][j] * w2[j*2 + c];
    out[b*2 + c] = acc;
  }
}

extern "C" void kernel_launch(void* const* d_in, const int* in_sizes, int n_in,
                              void* d_out, int out_size, void* d_ws, size_t ws_size,
                              hipStream_t stream){
  const float* x     = (const float*)d_in[0];
  const float* emb_w = (const float*)d_in[1];
  const float* emb_b = (const float*)d_in[2];
  const float* wq    = (const float*)d_in[3];
  const float* bq    = (const float*)d_in[4];
  const float* wk    = (const float*)d_in[5];
  const float* bk    = (const float*)d_in[6];
  const float* wv    = (const float*)d_in[7];
  const float* bv    = (const float*)d_in[8];
  const float* wo    = (const float*)d_in[9];
  const float* bo    = (const float*)d_in[10];
  const float* ff1w  = (const float*)d_in[11];
  const float* ff1b  = (const float*)d_in[12];
  const float* ff2w  = (const float*)d_in[13];
  const float* ff2b  = (const float*)d_in[14];
  const float* ln1g  = (const float*)d_in[15];
  const float* ln1b  = (const float*)d_in[16];
  const float* ln2g  = (const float*)d_in[17];
  const float* ln2b  = (const float*)d_in[18];
  const float* d1w   = (const float*)d_in[19];
  const float* d1b   = (const float*)d_in[20];
  const float* d2w   = (const float*)d_in[21];
  const float* d2b   = (const float*)d_in[22];

  // workspace layout (fp32): h | tmp | qb | kb | vb | aob | pooled  (~96 MB)
  // ff (8192x2048) overlays qb..aob (q/k/v/ao dead by the time FF runs)
  float* h      = (float*)d_ws;
  float* tmp    = h   + (size_t)NTOK*512;
  float* qb     = tmp + (size_t)NTOK*512;
  float* kb     = qb  + (size_t)NTOK*512;
  float* vb     = kb  + (size_t)NTOK*512;
  float* aob    = vb  + (size_t)NTOK*512;
  float* ff     = qb;
  float* pooled = aob + (size_t)NTOK*512;

  dim3 blk(16, 16);
  embed_kernel<<<NTOK, 256, 0, stream>>>(x, emb_w, emb_b, h);

  for (int l = 0; l < 2; ++l){
    const float* wq_l  = wq   + (size_t)l*512*512;
    const float* wk_l  = wk   + (size_t)l*512*512;
    const float* wv_l  = wv   + (size_t)l*512*512;
    const float* wo_l  = wo   + (size_t)l*512*512;
    const float* ff1w_l = ff1w + (size_t)l*512*2048;
    const float* ff2w_l = ff2w + (size_t)l*2048*512;

    gemm_f32<2><<<dim3(8, 128), blk, 0, stream>>>(h, wq_l, bq + l*512, qb, NTOK, 512, 512);
    gemm_f32<2><<<dim3(8, 128), blk, 0, stream>>>(h, wk_l, bk + l*512, kb, NTOK, 512, 512);
    gemm_f32<2><<<dim3(8, 128), blk, 0, stream>>>(h, wv_l, bv + l*512, vb, NTOK, 512, 512);

    attn_topk_kernel<<<16384, 256, 0, stream>>>(qb, kb, vb, aob);

    gemm_f32<0><<<dim3(8, 128), blk, 0, stream>>>(aob, wo_l, bo + l*512, tmp, NTOK, 512, 512);
    resid_ln_kernel<<<NTOK, 256, 0, stream>>>(h, tmp, ln1g + l*512, ln1b + l*512);

    gemm_f32<1><<<dim3(32, 128), blk, 0, stream>>>(h, ff1w_l, ff1b + l*2048, ff, NTOK, 2048, 512);
    gemm_f32<0><<<dim3(8, 128), blk, 0, stream>>>(ff, ff2w_l, ff2b + l*512, tmp, NTOK, 512, 2048);
    resid_ln_kernel<<<NTOK, 256, 0, stream>>>(h, tmp, ln2g + l*512, ln2b + l*512);
  }

  pool_kernel<<<dim3(2, 4), 256, 0, stream>>>(h, pooled);
  decoder_kernel<<<1, 256, 0, stream>>>(pooled, d1w, d1b, d2w, d2b, (float*)d_out);
}

// Round 3
// 3703.127 us; speedup vs baseline: 3.4221x; 3.4221x over previous
//
#include <hip/hip_runtime.h>
#include <cmath>

typedef unsigned short u16;
typedef __attribute__((ext_vector_type(8))) short short8;
typedef __attribute__((ext_vector_type(4))) float float4v;

#define S_LEN 2048
#define NTOK  8192   // B*S
#define TOPK  35

__device__ __forceinline__ u16 f2b(float f){
  unsigned int x = __float_as_uint(f);
  unsigned int r = (x + 0x7fffu + ((x >> 16) & 1u)) >> 16;
  return (u16)r;
}

// ---------------- embedding + sinusoidal PE ----------------
__global__ void embed_kernel(const float* __restrict__ x, const float* __restrict__ w,
                             const float* __restrict__ bias, float* __restrict__ h){
  int t = blockIdx.x;          // token 0..8191
  int tid = threadIdx.x;       // 0..255
  __shared__ float xs[64];
  if (tid < 64) xs[tid] = x[(size_t)t*64 + tid];
  __syncthreads();
  float acc0 = bias[tid];
  float acc1 = bias[tid + 256];
  #pragma unroll 8
  for (int k = 0; k < 64; ++k){
    float xv = xs[k];
    acc0 += xv * w[k*512 + tid];
    acc1 += xv * w[k*512 + tid + 256];
  }
  int s = t & (S_LEN - 1);
  const float neg_ln1e4_over_D = -9.210340371976184f / 512.f;
  int c0 = tid, c1 = tid + 256;
  float a0 = (float)s * expf((float)(c0 & ~1) * neg_ln1e4_over_D);
  float p0 = (c0 & 1) ? cosf(a0) : sinf(a0);
  float a1 = (float)s * expf((float)(c1 & ~1) * neg_ln1e4_over_D);
  float p1 = (c1 & 1) ? cosf(a1) : sinf(a1);
  h[(size_t)t*512 + c0] = acc0 + p0;
  h[(size_t)t*512 + c1] = acc1 + p1;
}

// ---------------- generic fp32 GEMM: C = A[M,K] @ W[K,N] + bias ----------------
// MODE 0: plain, MODE 1: relu,
// MODE 2: scatter fp32 to [B,H,S,DK] (N=512), MODE 3: scatter bf16 to [B,H,S,DK]
template<int MODE>
__global__ void gemm_f32(const float* __restrict__ A, const float* __restrict__ W,
                         const float* __restrict__ bias, float* __restrict__ C,
                         int M, int N, int K){
  __shared__ __align__(16) float As[16][64];
  __shared__ __align__(16) float Ws[16][64];
  int tx = threadIdx.x, ty = threadIdx.y;     // 16x16
  int tid = ty*16 + tx;
  int m0 = blockIdx.y * 64, n0 = blockIdx.x * 64;
  float acc[4][4];
  #pragma unroll
  for (int i = 0; i < 4; ++i)
    #pragma unroll
    for (int j = 0; j < 4; ++j) acc[i][j] = 0.f;

  int lm = tid >> 2;          // 0..63 (A row within tile)
  int lk = (tid & 3) * 4;     // 0,4,8,12
  int wk = tid >> 4;          // 0..15 (W k within tile)
  int wn = (tid & 15) * 4;    // 0..60

  for (int k0 = 0; k0 < K; k0 += 16){
    float4 av = *(const float4*)(A + (size_t)(m0 + lm)*K + k0 + lk);
    As[lk+0][lm] = av.x; As[lk+1][lm] = av.y; As[lk+2][lm] = av.z; As[lk+3][lm] = av.w;
    float4 wv = *(const float4*)(W + (size_t)(k0 + wk)*N + n0 + wn);
    Ws[wk][wn+0] = wv.x; Ws[wk][wn+1] = wv.y;
    Ws[wk][wn+2] = wv.z; Ws[wk][wn+3] = wv.w;
    __syncthreads();
    #pragma unroll
    for (int k = 0; k < 16; ++k){
      float4 a = *(const float4*)&As[k][ty*4];
      float4 b = *(const float4*)&Ws[k][tx*4];
      float ar[4] = {a.x, a.y, a.z, a.w};
      float br[4] = {b.x, b.y, b.z, b.w};
      #pragma unroll
      for (int i = 0; i < 4; ++i)
        #pragma unroll
        for (int j = 0; j < 4; ++j) acc[i][j] += ar[i]*br[j];
    }
    __syncthreads();
  }

  #pragma unroll
  for (int i = 0; i < 4; ++i){
    int row = m0 + ty*4 + i;
    #pragma unroll
    for (int j = 0; j < 4; ++j){
      int col = n0 + tx*4 + j;
      float v = acc[i][j] + bias[col];
      if (MODE == 1) v = fmaxf(v, 0.f);
      if (MODE == 2 || MODE == 3){
        int b = row >> 11, s = row & 2047;    // S=2048
        int hh = col >> 6, d = col & 63;      // DK=64
        size_t idx = (((size_t)(b*8 + hh))*2048 + s)*64 + d;
        if (MODE == 2) C[idx] = v;
        else           ((u16*)C)[idx] = f2b(v);
      } else {
        C[(size_t)row*N + col] = v;
      }
    }
  }
}

// ---------------- fused MFMA scores + top-35 + softmax + P@V[:35] ----------------
// Block: 256 thr (4 waves) handles one bh x 16-query tile. qb16/kb16 bf16 [B*H,S,64],
// vb fp32 [B*H,S,64]. Scores (x0.125) stored bf16 in 64KB LDS, then per-wave top-k.
__global__ __launch_bounds__(256) void attn_mfma_topk(
    const u16* __restrict__ qb16, const u16* __restrict__ kb16,
    const float* __restrict__ vb, float* __restrict__ aob){
  __shared__ u16 sc_lds[16][2048];   // 64 KB
  int tid  = threadIdx.x;
  int w    = tid >> 6, l = tid & 63;
  int quad = l >> 4,  m = l & 15;
  int bh = blockIdx.y;
  int q0 = blockIdx.x * 16;

  // A frags: A[m=lane&15][k=quad*8+j], two d-halves (0..31, 32..63)
  const u16* Qp = qb16 + ((size_t)bh*2048 + q0 + m)*64 + quad*8;
  short8 a0 = *(const short8*)Qp;
  short8 a1 = *(const short8*)(Qp + 32);

  // wave w covers keys [w*512, w*512+512)
  const u16* Kbase = kb16 + (size_t)bh*2048*64;
  for (int kt = 0; kt < 32; ++kt){
    int k0 = w*512 + kt*16;
    const u16* Kp = Kbase + (size_t)(k0 + m)*64 + quad*8;
    short8 b0 = *(const short8*)Kp;
    short8 b1 = *(const short8*)(Kp + 32);
    float4v acc = {0.f, 0.f, 0.f, 0.f};
    acc = __builtin_amdgcn_mfma_f32_16x16x32_bf16(a0, b0, acc, 0, 0, 0);
    acc = __builtin_amdgcn_mfma_f32_16x16x32_bf16(a1, b1, acc, 0, 0, 0);
    // C layout: row(query) = quad*4+r, col(key) = lane&15
    #pragma unroll
    for (int r = 0; r < 4; ++r)
      sc_lds[quad*4 + r][k0 + m] = f2b(acc[r] * 0.125f);
  }
  __syncthreads();

  const float* Vb = vb + (size_t)bh*2048*64 + l;   // lane = d
  int b = bh >> 3, hh = bh & 7;
  for (int qi = 0; qi < 4; ++qi){
    int q = w*4 + qi;
    // lane reads 32 scores (4 keys per ds_read_b64); key->slot mapping irrelevant
    const uint2* p = (const uint2*)&sc_lds[q][0];
    float sc[32];
    #pragma unroll
    for (int j = 0; j < 8; ++j){
      uint2 v2 = p[j*64 + l];
      sc[j*4+0] = __uint_as_float(v2.x << 16);
      sc[j*4+1] = __uint_as_float(v2.x & 0xffff0000u);
      sc[j*4+2] = __uint_as_float(v2.y << 16);
      sc[j*4+3] = __uint_as_float(v2.y & 0xffff0000u);
    }
    // iterative top-35 (descending); each round removes exactly one element
    float tv[TOPK];
    for (int r = 0; r < TOPK; ++r){
      float best = -INFINITY; int bslot = -1;
      #pragma unroll
      for (int j = 0; j < 32; ++j){ if (sc[j] > best){ best = sc[j]; bslot = j; } }
      float mmax = best;
      #pragma unroll
      for (int off = 32; off > 0; off >>= 1) mmax = fmaxf(mmax, __shfl_xor(mmax, off, 64));
      unsigned long long msk = __ballot(best == mmax);
      int owner = __ffsll((unsigned long long)msk) - 1;
      if (l == owner){
        #pragma unroll
        for (int j = 0; j < 32; ++j) if (j == bslot) sc[j] = -INFINITY;
      }
      tv[r] = mmax;
    }
    // softmax over sorted values; weight r pairs with V row r (reference quirk)
    float mx = tv[0], denom = 0.f;
    #pragma unroll
    for (int r = 0; r < TOPK; ++r){ tv[r] = expf(tv[r] - mx); denom += tv[r]; }
    float inv = 1.f / denom;
    float acc = 0.f;
    #pragma unroll
    for (int r = 0; r < TOPK; ++r) acc += tv[r] * Vb[(size_t)r*64];
    acc *= inv;
    int s = q0 + q;
    aob[(((size_t)(b*2048 + s))*8 + hh)*64 + l] = acc;
  }
}

// ---------------- h = LayerNorm(h + t) * g + b, in place ----------------
__global__ void resid_ln_kernel(float* __restrict__ h, const float* __restrict__ t,
                                const float* __restrict__ g, const float* __restrict__ b){
  int tok = blockIdx.x;
  int tid = threadIdx.x;        // 256 threads, 2 elems each
  size_t base = (size_t)tok * 512;
  float x0 = h[base + tid]       + t[base + tid];
  float x1 = h[base + tid + 256] + t[base + tid + 256];
  __shared__ float red[8];
  int wid = tid >> 6, lane = tid & 63;

  float s = x0 + x1;
  #pragma unroll
  for (int off = 32; off > 0; off >>= 1) s += __shfl_xor(s, off, 64);
  if (lane == 0) red[wid] = s;
  __syncthreads();
  float mean = (red[0] + red[1] + red[2] + red[3]) * (1.f/512.f);

  float d0 = x0 - mean, d1 = x1 - mean;
  float sq = d0*d0 + d1*d1;
  #pragma unroll
  for (int off = 32; off > 0; off >>= 1) sq += __shfl_xor(sq, off, 64);
  if (lane == 0) red[4 + wid] = sq;
  __syncthreads();
  float var = (red[4] + red[5] + red[6] + red[7]) * (1.f/512.f);
  float inv = rsqrtf(var + 1e-5f);
  h[base + tid]       = d0 * inv * g[tid]       + b[tid];
  h[base + tid + 256] = d1 * inv * g[tid + 256] + b[tid + 256];
}

// ---------------- mean over sequence ----------------
__global__ void pool_kernel(const float* __restrict__ h, float* __restrict__ pooled){
  int c = blockIdx.x * 256 + threadIdx.x;   // 0..511
  int b = blockIdx.y;
  const float* p = h + (size_t)b * 2048 * 512 + c;
  float acc = 0.f;
  for (int s = 0; s < 2048; ++s) acc += p[(size_t)s * 512];
  pooled[b*512 + c] = acc * (1.f/2048.f);
}

// ---------------- tiny decoder ----------------
__global__ void decoder_kernel(const float* __restrict__ pooled,
                               const float* __restrict__ w1, const float* __restrict__ b1,
                               const float* __restrict__ w2, const float* __restrict__ b2,
                               float* __restrict__ out){
  __shared__ float ps[4][512];
  __shared__ float hid[4][256];
  int tid = threadIdx.x;
  for (int i = tid; i < 2048; i += 256) ps[i >> 9][i & 511] = pooled[i];
  __syncthreads();
  float bb = b1[tid];
  for (int b = 0; b < 4; ++b){
    float acc = bb;
    for (int k = 0; k < 512; ++k) acc += ps[b][k] * w1[k*256 + tid];
    hid[b][tid] = fmaxf(acc, 0.f);
  }
  __syncthreads();
  if (tid < 8){
    int b = tid >> 1, c = tid & 1;
    float acc = b2[c];
    for (int j = 0; j < 256; ++j) acc += hid[b][j] * w2[j*2 + c];
    out[b*2 + c] = acc;
  }
}

extern "C" void kernel_launch(void* const* d_in, const int* in_sizes, int n_in,
                              void* d_out, int out_size, void* d_ws, size_t ws_size,
                              hipStream_t stream){
  const float* x     = (const float*)d_in[0];
  const float* emb_w = (const float*)d_in[1];
  const float* emb_b = (const float*)d_in[2];
  const float* wq    = (const float*)d_in[3];
  const float* bq    = (const float*)d_in[4];
  const float* wk    = (const float*)d_in[5];
  const float* bk    = (const float*)d_in[6];
  const float* wv    = (const float*)d_in[7];
  const float* bv    = (const float*)d_in[8];
  const float* wo    = (const float*)d_in[9];
  const float* bo    = (const float*)d_in[10];
  const float* ff1w  = (const float*)d_in[11];
  const float* ff1b  = (const float*)d_in[12];
  const float* ff2w  = (const float*)d_in[13];
  const float* ff2b  = (const float*)d_in[14];
  const float* ln1g  = (const float*)d_in[15];
  const float* ln1b  = (const float*)d_in[16];
  const float* ln2g  = (const float*)d_in[17];
  const float* ln2b  = (const float*)d_in[18];
  const float* d1w   = (const float*)d_in[19];
  const float* d1b   = (const float*)d_in[20];
  const float* d2w   = (const float*)d_in[21];
  const float* d2b   = (const float*)d_in[22];

  // workspace layout (fp32 slots): h | tmp | qb | kb | vb | aob | pooled (~96 MB)
  // qb/kb slots are reused as bf16 buffers (half-occupied); ff overlays qb..(dead after attn)
  float* h      = (float*)d_ws;
  float* tmp    = h   + (size_t)NTOK*512;
  float* qb     = tmp + (size_t)NTOK*512;
  float* kb     = qb  + (size_t)NTOK*512;
  float* vb     = kb  + (size_t)NTOK*512;
  float* aob    = vb  + (size_t)NTOK*512;
  float* ff     = qb;
  float* pooled = aob + (size_t)NTOK*512;
  u16* qb16 = (u16*)qb;
  u16* kb16 = (u16*)kb;

  dim3 blk(16, 16);
  embed_kernel<<<NTOK, 256, 0, stream>>>(x, emb_w, emb_b, h);

  for (int l = 0; l < 2; ++l){
    const float* wq_l  = wq   + (size_t)l*512*512;
    const float* wk_l  = wk   + (size_t)l*512*512;
    const float* wv_l  = wv   + (size_t)l*512*512;
    const float* wo_l  = wo   + (size_t)l*512*512;
    const float* ff1w_l = ff1w + (size_t)l*512*2048;
    const float* ff2w_l = ff2w + (size_t)l*2048*512;

    gemm_f32<3><<<dim3(8, 128), blk, 0, stream>>>(h, wq_l, bq + l*512, qb, NTOK, 512, 512);
    gemm_f32<3><<<dim3(8, 128), blk, 0, stream>>>(h, wk_l, bk + l*512, kb, NTOK, 512, 512);
    gemm_f32<2><<<dim3(8, 128), blk, 0, stream>>>(h, wv_l, bv + l*512, vb, NTOK, 512, 512);

    attn_mfma_topk<<<dim3(128, 32), 256, 0, stream>>>(qb16, kb16, vb, aob);

    gemm_f32<0><<<dim3(8, 128), blk, 0, stream>>>(aob, wo_l, bo + l*512, tmp, NTOK, 512, 512);
    resid_ln_kernel<<<NTOK, 256, 0, stream>>>(h, tmp, ln1g + l*512, ln1b + l*512);

    gemm_f32<1><<<dim3(32, 128), blk, 0, stream>>>(h, ff1w_l, ff1b + l*2048, ff, NTOK, 2048, 512);
    gemm_f32<0><<<dim3(8, 128), blk, 0, stream>>>(ff, ff2w_l, ff2b + l*512, tmp, NTOK, 512, 2048);
    resid_ln_kernel<<<NTOK, 256, 0, stream>>>(h, tmp, ln2g + l*512, ln2b + l*512);
  }

  pool_kernel<<<dim3(2, 4), 256, 0, stream>>>(h, pooled);
  decoder_kernel<<<1, 256, 0, stream>>>(pooled, d1w, d1b, d2w, d2b, (float*)d_out);
}

// Round 4
// 2695.692 us; speedup vs baseline: 4.7010x; 1.3737x over previous
//
#include <hip/hip_runtime.h>
#include <cmath>

typedef unsigned short u16;
typedef __attribute__((ext_vector_type(8))) short short8;
typedef __attribute__((ext_vector_type(4))) float float4v;

#define S_LEN 2048
#define NTOK  8192   // B*S
#define TOPK  35

__device__ __forceinline__ u16 f2b(float f){
  unsigned int x = __float_as_uint(f);
  unsigned int r = (x + 0x7fffu + ((x >> 16) & 1u)) >> 16;
  return (u16)r;
}

// ---------------- embedding + sinusoidal PE ----------------
__global__ void embed_kernel(const float* __restrict__ x, const float* __restrict__ w,
                             const float* __restrict__ bias, float* __restrict__ h){
  int t = blockIdx.x;          // token 0..8191
  int tid = threadIdx.x;       // 0..255
  __shared__ float xs[64];
  if (tid < 64) xs[tid] = x[(size_t)t*64 + tid];
  __syncthreads();
  float acc0 = bias[tid];
  float acc1 = bias[tid + 256];
  #pragma unroll 8
  for (int k = 0; k < 64; ++k){
    float xv = xs[k];
    acc0 += xv * w[k*512 + tid];
    acc1 += xv * w[k*512 + tid + 256];
  }
  int s = t & (S_LEN - 1);
  const float neg_ln1e4_over_D = -9.210340371976184f / 512.f;
  int c0 = tid, c1 = tid + 256;
  float a0 = (float)s * expf((float)(c0 & ~1) * neg_ln1e4_over_D);
  float p0 = (c0 & 1) ? cosf(a0) : sinf(a0);
  float a1 = (float)s * expf((float)(c1 & ~1) * neg_ln1e4_over_D);
  float p1 = (c1 & 1) ? cosf(a1) : sinf(a1);
  h[(size_t)t*512 + c0] = acc0 + p0;
  h[(size_t)t*512 + c1] = acc1 + p1;
}

// ---------------- generic fp32 GEMM: C = A[M,K] @ W[K,N] + bias ----------------
// MODE 0: plain, MODE 1: relu,
// MODE 2: scatter fp32 to [B,H,S,DK] (N=512), MODE 3: scatter bf16 to [B,H,S,DK]
template<int MODE>
__global__ void gemm_f32(const float* __restrict__ A, const float* __restrict__ W,
                         const float* __restrict__ bias, float* __restrict__ C,
                         int M, int N, int K){
  __shared__ __align__(16) float As[16][64];
  __shared__ __align__(16) float Ws[16][64];
  int tx = threadIdx.x, ty = threadIdx.y;     // 16x16
  int tid = ty*16 + tx;
  int m0 = blockIdx.y * 64, n0 = blockIdx.x * 64;
  float acc[4][4];
  #pragma unroll
  for (int i = 0; i < 4; ++i)
    #pragma unroll
    for (int j = 0; j < 4; ++j) acc[i][j] = 0.f;

  int lm = tid >> 2;          // 0..63 (A row within tile)
  int lk = (tid & 3) * 4;     // 0,4,8,12
  int wk = tid >> 4;          // 0..15 (W k within tile)
  int wn = (tid & 15) * 4;    // 0..60

  for (int k0 = 0; k0 < K; k0 += 16){
    float4 av = *(const float4*)(A + (size_t)(m0 + lm)*K + k0 + lk);
    As[lk+0][lm] = av.x; As[lk+1][lm] = av.y; As[lk+2][lm] = av.z; As[lk+3][lm] = av.w;
    float4 wv = *(const float4*)(W + (size_t)(k0 + wk)*N + n0 + wn);
    Ws[wk][wn+0] = wv.x; Ws[wk][wn+1] = wv.y;
    Ws[wk][wn+2] = wv.z; Ws[wk][wn+3] = wv.w;
    __syncthreads();
    #pragma unroll
    for (int k = 0; k < 16; ++k){
      float4 a = *(const float4*)&As[k][ty*4];
      float4 b = *(const float4*)&Ws[k][tx*4];
      float ar[4] = {a.x, a.y, a.z, a.w};
      float br[4] = {b.x, b.y, b.z, b.w};
      #pragma unroll
      for (int i = 0; i < 4; ++i)
        #pragma unroll
        for (int j = 0; j < 4; ++j) acc[i][j] += ar[i]*br[j];
    }
    __syncthreads();
  }

  #pragma unroll
  for (int i = 0; i < 4; ++i){
    int row = m0 + ty*4 + i;
    #pragma unroll
    for (int j = 0; j < 4; ++j){
      int col = n0 + tx*4 + j;
      float v = acc[i][j] + bias[col];
      if (MODE == 1) v = fmaxf(v, 0.f);
      if (MODE == 2 || MODE == 3){
        int b = row >> 11, s = row & 2047;    // S=2048
        int hh = col >> 6, d = col & 63;      // DK=64
        size_t idx = (((size_t)(b*8 + hh))*2048 + s)*64 + d;
        if (MODE == 2) C[idx] = v;
        else           ((u16*)C)[idx] = f2b(v);
      } else {
        C[(size_t)row*N + col] = v;
      }
    }
  }
}

// ---------------- fused MFMA scores + top-35 + softmax + P@V[:35] ----------------
// Block: 256 thr (4 waves) per (bh, 16-query tile). Scores bf16 in 64KB LDS.
// Top-k: per-lane bitonic sort (regs) -> sorted list back into the wave-private
// LDS row -> 35-round head-merge (one pop per round; bf16 dups rank-safe).
__global__ __launch_bounds__(256) void attn_mfma_topk(
    const u16* __restrict__ qb16, const u16* __restrict__ kb16,
    const float* __restrict__ vb, float* __restrict__ aob){
  __shared__ u16 sc_lds[16][2048];   // 64 KB
  int tid  = threadIdx.x;
  int w    = tid >> 6, l = tid & 63;
  int quad = l >> 4,  m = l & 15;
  int bh = blockIdx.y;
  int q0 = blockIdx.x * 16;

  // A frags: A[m=lane&15][k=quad*8+j], two d-halves (0..31, 32..63)
  const u16* Qp = qb16 + ((size_t)bh*2048 + q0 + m)*64 + quad*8;
  short8 a0 = *(const short8*)Qp;
  short8 a1 = *(const short8*)(Qp + 32);

  // wave w covers keys [w*512, w*512+512)
  const u16* Kbase = kb16 + (size_t)bh*2048*64;
  for (int kt = 0; kt < 32; ++kt){
    int k0 = w*512 + kt*16;
    const u16* Kp = Kbase + (size_t)(k0 + m)*64 + quad*8;
    short8 b0 = *(const short8*)Kp;
    short8 b1 = *(const short8*)(Kp + 32);
    float4v acc = {0.f, 0.f, 0.f, 0.f};
    acc = __builtin_amdgcn_mfma_f32_16x16x32_bf16(a0, b0, acc, 0, 0, 0);
    acc = __builtin_amdgcn_mfma_f32_16x16x32_bf16(a1, b1, acc, 0, 0, 0);
    // C layout: row(query) = quad*4+r, col(key) = lane&15
    #pragma unroll
    for (int r = 0; r < 4; ++r)
      sc_lds[quad*4 + r][k0 + m] = f2b(acc[r] * 0.125f);
  }
  __syncthreads();

  const float* Vb = vb + (size_t)bh*2048*64 + l;   // lane = d
  int b = bh >> 3, hh = bh & 7;
  for (int qi = 0; qi < 4; ++qi){
    int q = w*4 + qi;   // row q is read/overwritten ONLY by wave w = q>>2
    // lane reads 32 scores (4 keys per ds_read_b64)
    const uint2* p2 = (const uint2*)&sc_lds[q][0];
    float sc[32];
    #pragma unroll
    for (int j = 0; j < 8; ++j){
      uint2 v2 = p2[j*64 + l];
      sc[j*4+0] = __uint_as_float(v2.x << 16);
      sc[j*4+1] = __uint_as_float(v2.x & 0xffff0000u);
      sc[j*4+2] = __uint_as_float(v2.y << 16);
      sc[j*4+3] = __uint_as_float(v2.y & 0xffff0000u);
    }

    // per-lane bitonic sort, descending (fully static -> 2 VALU per CE)
    #pragma unroll
    for (int k = 2; k <= 32; k <<= 1){
      #pragma unroll
      for (int j = k >> 1; j > 0; j >>= 1){
        #pragma unroll
        for (int i = 0; i < 32; ++i){
          int ixj = i ^ j;
          if (ixj > i){
            float a = sc[i], bb = sc[ixj];
            float hi = fmaxf(a, bb), lo = fminf(a, bb);
            if ((i & k) == 0){ sc[i] = hi; sc[ixj] = lo; }
            else             { sc[i] = lo; sc[ixj] = hi; }
          }
        }
      }
    }

    // write sorted list into own row: element i at [q][i*64 + l] (2-way bank = free)
    u16* row = &sc_lds[q][0];
    #pragma unroll
    for (int i = 0; i < 32; ++i) row[i*64 + l] = (u16)(__float_as_uint(sc[i]) >> 16);

    // 35-round rank merge on per-lane heads
    float head = sc[0];
    int   p    = 0;
    float tv[TOPK];
    #pragma unroll
    for (int r = 0; r < TOPK; ++r){
      float mmax = head;
      #pragma unroll
      for (int off = 32; off > 0; off >>= 1) mmax = fmaxf(mmax, __shfl_xor(mmax, off, 64));
      tv[r] = mmax;
      unsigned long long msk = __ballot(head == mmax);
      int owner = __ffsll(msk) - 1;
      if (l == owner){
        ++p;
        head = (p < 32) ? __uint_as_float(((unsigned int)row[p*64 + l]) << 16)
                        : -INFINITY;
      }
    }

    // softmax over sorted values; weight r pairs with V row r (reference quirk)
    float mx = tv[0], denom = 0.f;
    #pragma unroll
    for (int r = 0; r < TOPK; ++r){ tv[r] = expf(tv[r] - mx); denom += tv[r]; }
    float inv = 1.f / denom;
    float acc = 0.f;
    #pragma unroll
    for (int r = 0; r < TOPK; ++r) acc += tv[r] * Vb[(size_t)r*64];
    acc *= inv;
    int s = q0 + q;
    aob[(((size_t)(b*2048 + s))*8 + hh)*64 + l] = acc;
  }
}

// ---------------- h = LayerNorm(h + t) * g + b, in place ----------------
__global__ void resid_ln_kernel(float* __restrict__ h, const float* __restrict__ t,
                                const float* __restrict__ g, const float* __restrict__ b){
  int tok = blockIdx.x;
  int tid = threadIdx.x;        // 256 threads, 2 elems each
  size_t base = (size_t)tok * 512;
  float x0 = h[base + tid]       + t[base + tid];
  float x1 = h[base + tid + 256] + t[base + tid + 256];
  __shared__ float red[8];
  int wid = tid >> 6, lane = tid & 63;

  float s = x0 + x1;
  #pragma unroll
  for (int off = 32; off > 0; off >>= 1) s += __shfl_xor(s, off, 64);
  if (lane == 0) red[wid] = s;
  __syncthreads();
  float mean = (red[0] + red[1] + red[2] + red[3]) * (1.f/512.f);

  float d0 = x0 - mean, d1 = x1 - mean;
  float sq = d0*d0 + d1*d1;
  #pragma unroll
  for (int off = 32; off > 0; off >>= 1) sq += __shfl_xor(sq, off, 64);
  if (lane == 0) red[4 + wid] = sq;
  __syncthreads();
  float var = (red[4] + red[5] + red[6] + red[7]) * (1.f/512.f);
  float inv = rsqrtf(var + 1e-5f);
  h[base + tid]       = d0 * inv * g[tid]       + b[tid];
  h[base + tid + 256] = d1 * inv * g[tid + 256] + b[tid + 256];
}

// ---------------- mean over sequence ----------------
__global__ void pool_kernel(const float* __restrict__ h, float* __restrict__ pooled){
  int c = blockIdx.x * 256 + threadIdx.x;   // 0..511
  int b = blockIdx.y;
  const float* p = h + (size_t)b * 2048 * 512 + c;
  float acc = 0.f;
  for (int s = 0; s < 2048; ++s) acc += p[(size_t)s * 512];
  pooled[b*512 + c] = acc * (1.f/2048.f);
}

// ---------------- tiny decoder ----------------
__global__ void decoder_kernel(const float* __restrict__ pooled,
                               const float* __restrict__ w1, const float* __restrict__ b1,
                               const float* __restrict__ w2, const float* __restrict__ b2,
                               float* __restrict__ out){
  __shared__ float ps[4][512];
  __shared__ float hid[4][256];
  int tid = threadIdx.x;
  for (int i = tid; i < 2048; i += 256) ps[i >> 9][i & 511] = pooled[i];
  __syncthreads();
  float bb = b1[tid];
  for (int b = 0; b < 4; ++b){
    float acc = bb;
    for (int k = 0; k < 512; ++k) acc += ps[b][k] * w1[k*256 + tid];
    hid[b][tid] = fmaxf(acc, 0.f);
  }
  __syncthreads();
  if (tid < 8){
    int b = tid >> 1, c = tid & 1;
    float acc = b2[c];
    for (int j = 0; j < 256; ++j) acc += hid[b][j] * w2[j*2 + c];
    out[b*2 + c] = acc;
  }
}

extern "C" void kernel_launch(void* const* d_in, const int* in_sizes, int n_in,
                              void* d_out, int out_size, void* d_ws, size_t ws_size,
                              hipStream_t stream){
  const float* x     = (const float*)d_in[0];
  const float* emb_w = (const float*)d_in[1];
  const float* emb_b = (const float*)d_in[2];
  const float* wq    = (const float*)d_in[3];
  const float* bq    = (const float*)d_in[4];
  const float* wk    = (const float*)d_in[5];
  const float* bk    = (const float*)d_in[6];
  const float* wv    = (const float*)d_in[7];
  const float* bv    = (const float*)d_in[8];
  const float* wo    = (const float*)d_in[9];
  const float* bo    = (const float*)d_in[10];
  const float* ff1w  = (const float*)d_in[11];
  const float* ff1b  = (const float*)d_in[12];
  const float* ff2w  = (const float*)d_in[13];
  const float* ff2b  = (const float*)d_in[14];
  const float* ln1g  = (const float*)d_in[15];
  const float* ln1b  = (const float*)d_in[16];
  const float* ln2g  = (const float*)d_in[17];
  const float* ln2b  = (const float*)d_in[18];
  const float* d1w   = (const float*)d_in[19];
  const float* d1b   = (const float*)d_in[20];
  const float* d2w   = (const float*)d_in[21];
  const float* d2b   = (const float*)d_in[22];

  // workspace layout (fp32 slots): h | tmp | qb | kb | vb | aob | pooled (~96 MB)
  // qb/kb slots reused as bf16; ff overlays qb.. (q/k dead when FF runs)
  float* h      = (float*)d_ws;
  float* tmp    = h   + (size_t)NTOK*512;
  float* qb     = tmp + (size_t)NTOK*512;
  float* kb     = qb  + (size_t)NTOK*512;
  float* vb     = kb  + (size_t)NTOK*512;
  float* aob    = vb  + (size_t)NTOK*512;
  float* ff     = qb;
  float* pooled = aob + (size_t)NTOK*512;
  u16* qb16 = (u16*)qb;
  u16* kb16 = (u16*)kb;

  dim3 blk(16, 16);
  embed_kernel<<<NTOK, 256, 0, stream>>>(x, emb_w, emb_b, h);

  for (int l = 0; l < 2; ++l){
    const float* wq_l  = wq   + (size_t)l*512*512;
    const float* wk_l  = wk   + (size_t)l*512*512;
    const float* wv_l  = wv   + (size_t)l*512*512;
    const float* wo_l  = wo   + (size_t)l*512*512;
    const float* ff1w_l = ff1w + (size_t)l*512*2048;
    const float* ff2w_l = ff2w + (size_t)l*2048*512;

    gemm_f32<3><<<dim3(8, 128), blk, 0, stream>>>(h, wq_l, bq + l*512, qb, NTOK, 512, 512);
    gemm_f32<3><<<dim3(8, 128), blk, 0, stream>>>(h, wk_l, bk + l*512, kb, NTOK, 512, 512);
    gemm_f32<2><<<dim3(8, 128), blk, 0, stream>>>(h, wv_l, bv + l*512, vb, NTOK, 512, 512);

    attn_mfma_topk<<<dim3(128, 32), 256, 0, stream>>>(qb16, kb16, vb, aob);

    gemm_f32<0><<<dim3(8, 128), blk, 0, stream>>>(aob, wo_l, bo + l*512, tmp, NTOK, 512, 512);
    resid_ln_kernel<<<NTOK, 256, 0, stream>>>(h, tmp, ln1g + l*512, ln1b + l*512);

    gemm_f32<1><<<dim3(32, 128), blk, 0, stream>>>(h, ff1w_l, ff1b + l*2048, ff, NTOK, 2048, 512);
    gemm_f32<0><<<dim3(8, 128), blk, 0, stream>>>(ff, ff2w_l, ff2b + l*512, tmp, NTOK, 512, 2048);
    resid_ln_kernel<<<NTOK, 256, 0, stream>>>(h, tmp, ln2g + l*512, ln2b + l*512);
  }

  pool_kernel<<<dim3(2, 4), 256, 0, stream>>>(h, pooled);
  decoder_kernel<<<1, 256, 0, stream>>>(pooled, d1w, d1b, d2w, d2b, (float*)d_out);
}

// Round 5
// 1544.231 us; speedup vs baseline: 8.2062x; 1.7457x over previous
//
#include <hip/hip_runtime.h>
#include <cmath>

typedef unsigned short u16;
typedef __attribute__((ext_vector_type(8))) short short8;
typedef __attribute__((ext_vector_type(4))) float float4v;

#define S_LEN 2048
#define NTOK  8192   // B*S
#define TOPK  35
#define NT512 ((size_t)NTOK*512)

__device__ __forceinline__ u16 f2b(float f){
  unsigned int x = __float_as_uint(f);
  unsigned int r = (x + 0x7fffu + ((x >> 16) & 1u)) >> 16;
  return (u16)r;
}

// ---------------- weight transpose + bf16 convert: Wt[n][k] = bf16(W[k][n]) ----------------
__global__ void convert_wt(const float* __restrict__ W, u16* __restrict__ Wt, int K, int N){
  __shared__ u16 t[32][33];
  int k0 = blockIdx.y*32, n0 = blockIdx.x*32;
  int tx = threadIdx.x, ty = threadIdx.y;   // 32x8
  #pragma unroll
  for (int i = ty; i < 32; i += 8)
    t[i][tx] = f2b(W[(size_t)(k0+i)*N + n0+tx]);
  __syncthreads();
  #pragma unroll
  for (int i = ty; i < 32; i += 8)
    Wt[(size_t)(n0+i)*K + k0+tx] = t[tx][i];
}

// ---------------- embedding + sinusoidal PE (writes fp32 h + bf16 h16) ----------------
__global__ void embed_kernel(const float* __restrict__ x, const float* __restrict__ w,
                             const float* __restrict__ bias, float* __restrict__ h,
                             u16* __restrict__ h16){
  int t = blockIdx.x;          // token 0..8191
  int tid = threadIdx.x;       // 0..255
  __shared__ float xs[64];
  if (tid < 64) xs[tid] = x[(size_t)t*64 + tid];
  __syncthreads();
  float acc0 = bias[tid];
  float acc1 = bias[tid + 256];
  #pragma unroll 8
  for (int k = 0; k < 64; ++k){
    float xv = xs[k];
    acc0 += xv * w[k*512 + tid];
    acc1 += xv * w[k*512 + tid + 256];
  }
  int s = t & (S_LEN - 1);
  const float neg_ln1e4_over_D = -9.210340371976184f / 512.f;
  int c0 = tid, c1 = tid + 256;
  float a0 = (float)s * expf((float)(c0 & ~1) * neg_ln1e4_over_D);
  float p0 = (c0 & 1) ? cosf(a0) : sinf(a0);
  float a1 = (float)s * expf((float)(c1 & ~1) * neg_ln1e4_over_D);
  float p1 = (c1 & 1) ? cosf(a1) : sinf(a1);
  float v0 = acc0 + p0, v1 = acc1 + p1;
  h[(size_t)t*512 + c0] = v0;  h16[(size_t)t*512 + c0] = f2b(v0);
  h[(size_t)t*512 + c1] = v1;  h16[(size_t)t*512 + c1] = f2b(v1);
}

// ---------------- bf16 MFMA GEMM: C = A[M,K](bf16) @ Bt[N,K]^T(bf16) + bias ----------------
// 128x128 tile, BK=64, 4 waves (2x2 of 64x64), 4x4 16x16x32 MFMA per wave.
// XOR-swizzled LDS staging: slot (row,sc) holds data chunk sc^(row&7).
// EPI 0: fp32 C[M,N];  EPI 1: relu -> bf16 C16a[M,N];
// EPI 2: fused QKV (N=1536): n<512 -> q bf16 scatter, <1024 -> k bf16, else v fp32 scatter.
template<int EPI>
__global__ __launch_bounds__(256) void gemm_mfma(
    const u16* __restrict__ A, const u16* __restrict__ Bt,
    const float* __restrict__ bias0, const float* __restrict__ bias1,
    const float* __restrict__ bias2,
    float* __restrict__ Cf, u16* __restrict__ C16a, u16* __restrict__ C16b,
    float* __restrict__ Cv, int M, int N, int K){
  __shared__ __align__(16) u16 As[128*64];
  __shared__ __align__(16) u16 Bs[128*64];
  int tid = threadIdx.x;
  int w = tid >> 6, l = tid & 63, quad = l >> 4, m = l & 15;
  int m0 = blockIdx.y*128, n0 = blockIdx.x*128;
  int mh = (w >> 1)*64, nh = (w & 1)*64;
  float4v acc[4][4];
  #pragma unroll
  for (int i = 0; i < 4; ++i)
    #pragma unroll
    for (int j = 0; j < 4; ++j) acc[i][j] = (float4v){0.f,0.f,0.f,0.f};

  for (int kt = 0; kt < K; kt += 64){
    #pragma unroll
    for (int c = 0; c < 4; ++c){
      int g = c*256 + tid;
      int row = g >> 3, sc = g & 7, dc = sc ^ (row & 7);
      uint4 av = *(const uint4*)(A  + (size_t)(m0+row)*K + kt + dc*8);
      uint4 bv = *(const uint4*)(Bt + (size_t)(n0+row)*K + kt + dc*8);
      *(uint4*)(As + (size_t)g*8) = av;
      *(uint4*)(Bs + (size_t)g*8) = bv;
    }
    __syncthreads();
    #pragma unroll
    for (int kk = 0; kk < 2; ++kk){
      short8 af[4], bf[4];
      #pragma unroll
      for (int i = 0; i < 4; ++i){
        int dcx = kk*4 + quad;
        int ra = mh + i*16 + m;
        af[i] = *(const short8*)(As + (size_t)(ra*8 + (dcx ^ (ra & 7)))*8);
        int rb = nh + i*16 + m;
        bf[i] = *(const short8*)(Bs + (size_t)(rb*8 + (dcx ^ (rb & 7)))*8);
      }
      #pragma unroll
      for (int i = 0; i < 4; ++i)
        #pragma unroll
        for (int j = 0; j < 4; ++j)
          acc[i][j] = __builtin_amdgcn_mfma_f32_16x16x32_bf16(af[i], bf[j], acc[i][j], 0, 0, 0);
    }
    __syncthreads();
  }

  // C/D layout: row_local = quad*4+r, col_local = m
  #pragma unroll
  for (int i = 0; i < 4; ++i){
    #pragma unroll
    for (int j = 0; j < 4; ++j){
      int col = n0 + nh + j*16 + m;
      #pragma unroll
      for (int r = 0; r < 4; ++r){
        int row = m0 + mh + i*16 + quad*4 + r;
        float v = acc[i][j][r];
        if (EPI == 0){
          Cf[(size_t)row*N + col] = v + bias0[col];
        } else if (EPI == 1){
          C16a[(size_t)row*N + col] = f2b(fmaxf(v + bias0[col], 0.f));
        } else {
          int sel = col >> 9, n5 = col & 511;
          const float* bp = (sel == 0) ? bias0 : (sel == 1) ? bias1 : bias2;
          float vv = v + bp[n5];
          int d = n5 & 63, hh = n5 >> 6;
          int b = row >> 11, s = row & 2047;
          size_t idx = (((size_t)(b*8 + hh))*2048 + s)*64 + d;
          if (sel == 0)      C16a[idx] = f2b(vv);
          else if (sel == 1) C16b[idx] = f2b(vv);
          else               Cv[idx]  = vv;
        }
      }
    }
  }
}

// ---------------- fused MFMA scores + top-35 + softmax + P@V[:35] ----------------
__global__ __launch_bounds__(256) void attn_mfma_topk(
    const u16* __restrict__ qb16, const u16* __restrict__ kb16,
    const float* __restrict__ vb, u16* __restrict__ aob16){
  __shared__ u16 sc_lds[16][2048];   // 64 KB
  int tid  = threadIdx.x;
  int w    = tid >> 6, l = tid & 63;
  int quad = l >> 4,  m = l & 15;
  int bh = blockIdx.y;
  int q0 = blockIdx.x * 16;

  const u16* Qp = qb16 + ((size_t)bh*2048 + q0 + m)*64 + quad*8;
  short8 a0 = *(const short8*)Qp;
  short8 a1 = *(const short8*)(Qp + 32);

  const u16* Kbase = kb16 + (size_t)bh*2048*64;
  for (int kt = 0; kt < 32; ++kt){
    int k0 = w*512 + kt*16;
    const u16* Kp = Kbase + (size_t)(k0 + m)*64 + quad*8;
    short8 b0 = *(const short8*)Kp;
    short8 b1 = *(const short8*)(Kp + 32);
    float4v acc = {0.f, 0.f, 0.f, 0.f};
    acc = __builtin_amdgcn_mfma_f32_16x16x32_bf16(a0, b0, acc, 0, 0, 0);
    acc = __builtin_amdgcn_mfma_f32_16x16x32_bf16(a1, b1, acc, 0, 0, 0);
    #pragma unroll
    for (int r = 0; r < 4; ++r)
      sc_lds[quad*4 + r][k0 + m] = f2b(acc[r] * 0.125f);
  }
  __syncthreads();

  const float* Vb = vb + (size_t)bh*2048*64 + l;   // lane = d
  int b = bh >> 3, hh = bh & 7;
  for (int qi = 0; qi < 4; ++qi){
    int q = w*4 + qi;   // row q touched only by wave w = q>>2
    const uint2* p2 = (const uint2*)&sc_lds[q][0];
    float sc[32];
    #pragma unroll
    for (int j = 0; j < 8; ++j){
      uint2 v2 = p2[j*64 + l];
      sc[j*4+0] = __uint_as_float(v2.x << 16);
      sc[j*4+1] = __uint_as_float(v2.x & 0xffff0000u);
      sc[j*4+2] = __uint_as_float(v2.y << 16);
      sc[j*4+3] = __uint_as_float(v2.y & 0xffff0000u);
    }

    // per-lane bitonic sort, descending
    #pragma unroll
    for (int k = 2; k <= 32; k <<= 1){
      #pragma unroll
      for (int j = k >> 1; j > 0; j >>= 1){
        #pragma unroll
        for (int i = 0; i < 32; ++i){
          int ixj = i ^ j;
          if (ixj > i){
            float a = sc[i], bb = sc[ixj];
            float hi = fmaxf(a, bb), lo = fminf(a, bb);
            if ((i & k) == 0){ sc[i] = hi; sc[ixj] = lo; }
            else             { sc[i] = lo; sc[ixj] = hi; }
          }
        }
      }
    }

    u16* row = &sc_lds[q][0];
    #pragma unroll
    for (int i = 0; i < 32; ++i) row[i*64 + l] = (u16)(__float_as_uint(sc[i]) >> 16);

    // 35-round rank merge on per-lane heads
    float head = sc[0];
    int   p    = 0;
    float tv[TOPK];
    #pragma unroll
    for (int r = 0; r < TOPK; ++r){
      float mmax = head;
      #pragma unroll
      for (int off = 32; off > 0; off >>= 1) mmax = fmaxf(mmax, __shfl_xor(mmax, off, 64));
      tv[r] = mmax;
      unsigned long long msk = __ballot(head == mmax);
      int owner = __ffsll(msk) - 1;
      if (l == owner){
        ++p;
        head = (p < 32) ? __uint_as_float(((unsigned int)row[p*64 + l]) << 16)
                        : -INFINITY;
      }
    }

    float mx = tv[0], denom = 0.f;
    #pragma unroll
    for (int r = 0; r < TOPK; ++r){ tv[r] = expf(tv[r] - mx); denom += tv[r]; }
    float inv = 1.f / denom;
    float acc = 0.f;
    #pragma unroll
    for (int r = 0; r < TOPK; ++r) acc += tv[r] * Vb[(size_t)r*64];
    acc *= inv;
    int s = q0 + q;
    aob16[(((size_t)(b*2048 + s))*8 + hh)*64 + l] = f2b(acc);
  }
}

// ---------------- h = LayerNorm(h + t) * g + b, in place; also bf16 copy ----------------
__global__ void resid_ln_kernel(float* __restrict__ h, const float* __restrict__ t,
                                const float* __restrict__ g, const float* __restrict__ b,
                                u16* __restrict__ h16){
  int tok = blockIdx.x;
  int tid = threadIdx.x;        // 256 threads, 2 elems each
  size_t base = (size_t)tok * 512;
  float x0 = h[base + tid]       + t[base + tid];
  float x1 = h[base + tid + 256] + t[base + tid + 256];
  __shared__ float red[8];
  int wid = tid >> 6, lane = tid & 63;

  float s = x0 + x1;
  #pragma unroll
  for (int off = 32; off > 0; off >>= 1) s += __shfl_xor(s, off, 64);
  if (lane == 0) red[wid] = s;
  __syncthreads();
  float mean = (red[0] + red[1] + red[2] + red[3]) * (1.f/512.f);

  float d0 = x0 - mean, d1 = x1 - mean;
  float sq = d0*d0 + d1*d1;
  #pragma unroll
  for (int off = 32; off > 0; off >>= 1) sq += __shfl_xor(sq, off, 64);
  if (lane == 0) red[4 + wid] = sq;
  __syncthreads();
  float var = (red[4] + red[5] + red[6] + red[7]) * (1.f/512.f);
  float inv = rsqrtf(var + 1e-5f);
  float o0 = d0 * inv * g[tid]       + b[tid];
  float o1 = d1 * inv * g[tid + 256] + b[tid + 256];
  h[base + tid]         = o0;  h16[base + tid]       = f2b(o0);
  h[base + tid + 256]   = o1;  h16[base + tid + 256] = f2b(o1);
}

// ---------------- mean over sequence ----------------
__global__ void pool_kernel(const float* __restrict__ h, float* __restrict__ pooled){
  int c = blockIdx.x * 256 + threadIdx.x;   // 0..511
  int b = blockIdx.y;
  const float* p = h + (size_t)b * 2048 * 512 + c;
  float acc = 0.f;
  for (int s = 0; s < 2048; ++s) acc += p[(size_t)s * 512];
  pooled[b*512 + c] = acc * (1.f/2048.f);
}

// ---------------- tiny decoder ----------------
__global__ void decoder_kernel(const float* __restrict__ pooled,
                               const float* __restrict__ w1, const float* __restrict__ b1,
                               const float* __restrict__ w2, const float* __restrict__ b2,
                               float* __restrict__ out){
  __shared__ float ps[4][512];
  __shared__ float hid[4][256];
  int tid = threadIdx.x;
  for (int i = tid; i < 2048; i += 256) ps[i >> 9][i & 511] = pooled[i];
  __syncthreads();
  float bb = b1[tid];
  for (int b = 0; b < 4; ++b){
    float acc = bb;
    for (int k = 0; k < 512; ++k) acc += ps[b][k] * w1[k*256 + tid];
    hid[b][tid] = fmaxf(acc, 0.f);
  }
  __syncthreads();
  if (tid < 8){
    int b = tid >> 1, c = tid & 1;
    float acc = b2[c];
    for (int j = 0; j < 256; ++j) acc += hid[b][j] * w2[j*2 + c];
    out[b*2 + c] = acc;
  }
}

extern "C" void kernel_launch(void* const* d_in, const int* in_sizes, int n_in,
                              void* d_out, int out_size, void* d_ws, size_t ws_size,
                              hipStream_t stream){
  const float* x     = (const float*)d_in[0];
  const float* emb_w = (const float*)d_in[1];
  const float* emb_b = (const float*)d_in[2];
  const float* wq    = (const float*)d_in[3];
  const float* bq    = (const float*)d_in[4];
  const float* wk    = (const float*)d_in[5];
  const float* bk    = (const float*)d_in[6];
  const float* wv    = (const float*)d_in[7];
  const float* bv    = (const float*)d_in[8];
  const float* wo    = (const float*)d_in[9];
  const float* bo    = (const float*)d_in[10];
  const float* ff1w  = (const float*)d_in[11];
  const float* ff1b  = (const float*)d_in[12];
  const float* ff2w  = (const float*)d_in[13];
  const float* ff2b  = (const float*)d_in[14];
  const float* ln1g  = (const float*)d_in[15];
  const float* ln1b  = (const float*)d_in[16];
  const float* ln2g  = (const float*)d_in[17];
  const float* ln2b  = (const float*)d_in[18];
  const float* d1w   = (const float*)d_in[19];
  const float* d1b   = (const float*)d_in[20];
  const float* d2w   = (const float*)d_in[21];
  const float* d2b   = (const float*)d_in[22];

  // ---- workspace layout (~92 MB) ----
  // f32: h(16M) tmp(16M) | u16: h16(8M) q16(8M) k16(8M) | f32 vb(16M) | u16 aob16(8M)
  // ff16 (32M bf16, 8192x2048) overlays q16+k16+vb (dead when FF runs)
  // u16 wt region (12M): per-layer wt_qkv[1536][512], wt_wo[512][512], wt_ff1[2048][512], wt_ff2[512][2048]
  float* h      = (float*)d_ws;
  float* tmp    = h + NT512;
  u16*   u      = (u16*)(tmp + NT512);
  u16*   h16    = u;
  u16*   q16    = u + NT512;
  u16*   k16    = u + 2*NT512;
  float* vb     = (float*)(u + 3*NT512);
  u16*   ff16   = q16;
  u16*   aob16  = (u16*)(vb + NT512);
  u16*   wt     = aob16 + NT512;
  u16*   wt_qkv = wt;                          // 2 x 1536*512
  u16*   wt_wo  = wt_qkv + (size_t)2*1536*512; // 2 x 512*512
  u16*   wt_ff1 = wt_wo  + (size_t)2*512*512;  // 2 x 2048*512
  u16*   wt_ff2 = wt_ff1 + (size_t)2*2048*512; // 2 x 512*2048
  float* pooled = (float*)(wt_ff2 + (size_t)2*512*2048);

  dim3 tblk(32, 8);
  for (int l = 0; l < 2; ++l){
    convert_wt<<<dim3(16, 16), tblk, 0, stream>>>(wq + (size_t)l*512*512, wt_qkv + (size_t)l*1536*512,            512, 512);
    convert_wt<<<dim3(16, 16), tblk, 0, stream>>>(wk + (size_t)l*512*512, wt_qkv + (size_t)l*1536*512 + 512*512,  512, 512);
    convert_wt<<<dim3(16, 16), tblk, 0, stream>>>(wv + (size_t)l*512*512, wt_qkv + (size_t)l*1536*512 + 1024*512, 512, 512);
    convert_wt<<<dim3(16, 16), tblk, 0, stream>>>(wo + (size_t)l*512*512, wt_wo + (size_t)l*512*512, 512, 512);
    convert_wt<<<dim3(64, 16), tblk, 0, stream>>>(ff1w + (size_t)l*512*2048, wt_ff1 + (size_t)l*2048*512, 512, 2048);
    convert_wt<<<dim3(16, 64), tblk, 0, stream>>>(ff2w + (size_t)l*2048*512, wt_ff2 + (size_t)l*512*2048, 2048, 512);
  }

  embed_kernel<<<NTOK, 256, 0, stream>>>(x, emb_w, emb_b, h, h16);

  for (int l = 0; l < 2; ++l){
    // fused QKV: N=1536, scatter epilogue
    gemm_mfma<2><<<dim3(12, 64), 256, 0, stream>>>(
        h16, wt_qkv + (size_t)l*1536*512,
        bq + l*512, bk + l*512, bv + l*512,
        nullptr, q16, k16, vb, NTOK, 1536, 512);

    attn_mfma_topk<<<dim3(128, 32), 256, 0, stream>>>(q16, k16, vb, aob16);

    gemm_mfma<0><<<dim3(4, 64), 256, 0, stream>>>(
        aob16, wt_wo + (size_t)l*512*512, bo + l*512, nullptr, nullptr,
        tmp, nullptr, nullptr, nullptr, NTOK, 512, 512);
    resid_ln_kernel<<<NTOK, 256, 0, stream>>>(h, tmp, ln1g + l*512, ln1b + l*512, h16);

    gemm_mfma<1><<<dim3(16, 64), 256, 0, stream>>>(
        h16, wt_ff1 + (size_t)l*2048*512, ff1b + l*2048, nullptr, nullptr,
        nullptr, ff16, nullptr, nullptr, NTOK, 2048, 512);
    gemm_mfma<0><<<dim3(4, 64), 256, 0, stream>>>(
        ff16, wt_ff2 + (size_t)l*512*2048, ff2b + l*512, nullptr, nullptr,
        tmp, nullptr, nullptr, nullptr, NTOK, 512, 2048);
    resid_ln_kernel<<<NTOK, 256, 0, stream>>>(h, tmp, ln2g + l*512, ln2b + l*512, h16);
  }

  pool_kernel<<<dim3(2, 4), 256, 0, stream>>>(h, pooled);
  decoder_kernel<<<1, 256, 0, stream>>>(pooled, d1w, d1b, d2w, d2b, (float*)d_out);
}

// Round 6
// 1087.217 us; speedup vs baseline: 11.6557x; 1.4204x over previous
//
#include <hip/hip_runtime.h>
#include <cmath>

typedef unsigned short u16;
typedef __attribute__((ext_vector_type(8))) short short8;
typedef __attribute__((ext_vector_type(4))) float float4v;

#define S_LEN 2048
#define NTOK  8192   // B*S
#define TOPK  35
#define NT512 ((size_t)NTOK*512)

__device__ __forceinline__ u16 f2b(float f){
  unsigned int x = __float_as_uint(f);
  unsigned int r = (x + 0x7fffu + ((x >> 16) & 1u)) >> 16;
  return (u16)r;
}
__device__ __forceinline__ float b2f16(u16 u){
  return __uint_as_float(((unsigned int)u) << 16);
}

// ---------------- weight transpose + bf16 convert: Wt[n][k] = bf16(W[k][n]) ----------------
__global__ void convert_wt(const float* __restrict__ W, u16* __restrict__ Wt, int K, int N){
  __shared__ u16 t[32][33];
  int k0 = blockIdx.y*32, n0 = blockIdx.x*32;
  int tx = threadIdx.x, ty = threadIdx.y;   // 32x8
  #pragma unroll
  for (int i = ty; i < 32; i += 8)
    t[i][tx] = f2b(W[(size_t)(k0+i)*N + n0+tx]);
  __syncthreads();
  #pragma unroll
  for (int i = ty; i < 32; i += 8)
    Wt[(size_t)(n0+i)*K + k0+tx] = t[tx][i];
}

// ---------------- embedding + sinusoidal PE (writes fp32 h + bf16 h16) ----------------
__global__ void embed_kernel(const float* __restrict__ x, const float* __restrict__ w,
                             const float* __restrict__ bias, float* __restrict__ h,
                             u16* __restrict__ h16){
  int t = blockIdx.x;          // token 0..8191
  int tid = threadIdx.x;       // 0..255
  __shared__ float xs[64];
  if (tid < 64) xs[tid] = x[(size_t)t*64 + tid];
  __syncthreads();
  float acc0 = bias[tid];
  float acc1 = bias[tid + 256];
  #pragma unroll 8
  for (int k = 0; k < 64; ++k){
    float xv = xs[k];
    acc0 += xv * w[k*512 + tid];
    acc1 += xv * w[k*512 + tid + 256];
  }
  int s = t & (S_LEN - 1);
  const float neg_ln1e4_over_D = -9.210340371976184f / 512.f;
  int c0 = tid, c1 = tid + 256;
  float a0 = (float)s * expf((float)(c0 & ~1) * neg_ln1e4_over_D);
  float p0 = (c0 & 1) ? cosf(a0) : sinf(a0);
  float a1 = (float)s * expf((float)(c1 & ~1) * neg_ln1e4_over_D);
  float p1 = (c1 & 1) ? cosf(a1) : sinf(a1);
  float v0 = acc0 + p0, v1 = acc1 + p1;
  h[(size_t)t*512 + c0] = v0;  h16[(size_t)t*512 + c0] = f2b(v0);
  h[(size_t)t*512 + c1] = v1;  h16[(size_t)t*512 + c1] = f2b(v1);
}

// ---------------- bf16 MFMA GEMM: C = A[M,K](bf16) @ Bt[N,K]^T(bf16) + bias ----------------
// 128x128 tile, BK=64, 4 waves (2x2 of 64x64), 4x4 16x16x32 MFMA per wave.
// XOR-swizzled LDS staging. EPI 0: fp32 C; EPI 1: relu->bf16; EPI 2: fused QKV scatter.
template<int EPI>
__global__ __launch_bounds__(256) void gemm_mfma(
    const u16* __restrict__ A, const u16* __restrict__ Bt,
    const float* __restrict__ bias0, const float* __restrict__ bias1,
    const float* __restrict__ bias2,
    float* __restrict__ Cf, u16* __restrict__ C16a, u16* __restrict__ C16b,
    float* __restrict__ Cv, int M, int N, int K){
  __shared__ __align__(16) u16 As[128*64];
  __shared__ __align__(16) u16 Bs[128*64];
  int tid = threadIdx.x;
  int w = tid >> 6, l = tid & 63, quad = l >> 4, m = l & 15;
  int m0 = blockIdx.y*128, n0 = blockIdx.x*128;
  int mh = (w >> 1)*64, nh = (w & 1)*64;
  float4v acc[4][4];
  #pragma unroll
  for (int i = 0; i < 4; ++i)
    #pragma unroll
    for (int j = 0; j < 4; ++j) acc[i][j] = (float4v){0.f,0.f,0.f,0.f};

  for (int kt = 0; kt < K; kt += 64){
    #pragma unroll
    for (int c = 0; c < 4; ++c){
      int g = c*256 + tid;
      int row = g >> 3, sc = g & 7, dc = sc ^ (row & 7);
      uint4 av = *(const uint4*)(A  + (size_t)(m0+row)*K + kt + dc*8);
      uint4 bv = *(const uint4*)(Bt + (size_t)(n0+row)*K + kt + dc*8);
      *(uint4*)(As + (size_t)g*8) = av;
      *(uint4*)(Bs + (size_t)g*8) = bv;
    }
    __syncthreads();
    #pragma unroll
    for (int kk = 0; kk < 2; ++kk){
      short8 af[4], bf[4];
      #pragma unroll
      for (int i = 0; i < 4; ++i){
        int dcx = kk*4 + quad;
        int ra = mh + i*16 + m;
        af[i] = *(const short8*)(As + (size_t)(ra*8 + (dcx ^ (ra & 7)))*8);
        int rb = nh + i*16 + m;
        bf[i] = *(const short8*)(Bs + (size_t)(rb*8 + (dcx ^ (rb & 7)))*8);
      }
      #pragma unroll
      for (int i = 0; i < 4; ++i)
        #pragma unroll
        for (int j = 0; j < 4; ++j)
          acc[i][j] = __builtin_amdgcn_mfma_f32_16x16x32_bf16(af[i], bf[j], acc[i][j], 0, 0, 0);
    }
    __syncthreads();
  }

  // C/D layout: row_local = quad*4+r, col_local = m
  #pragma unroll
  for (int i = 0; i < 4; ++i){
    #pragma unroll
    for (int j = 0; j < 4; ++j){
      int col = n0 + nh + j*16 + m;
      #pragma unroll
      for (int r = 0; r < 4; ++r){
        int row = m0 + mh + i*16 + quad*4 + r;
        float v = acc[i][j][r];
        if (EPI == 0){
          Cf[(size_t)row*N + col] = v + bias0[col];
        } else if (EPI == 1){
          C16a[(size_t)row*N + col] = f2b(fmaxf(v + bias0[col], 0.f));
        } else {
          int sel = col >> 9, n5 = col & 511;
          const float* bp = (sel == 0) ? bias0 : (sel == 1) ? bias1 : bias2;
          float vv = v + bp[n5];
          int d = n5 & 63, hh = n5 >> 6;
          int b = row >> 11, s = row & 2047;
          size_t idx = (((size_t)(b*8 + hh))*2048 + s)*64 + d;
          if (sel == 0)      C16a[idx] = f2b(vv);
          else if (sel == 1) C16b[idx] = f2b(vv);
          else               Cv[idx]  = vv;
        }
      }
    }
  }
}

// ---------------- fused MFMA scores + top-35 + softmax + P@V[:35] ----------------
// 512 thr (8 waves) per (bh, 16-query tile). Score phase: wave w covers keys
// [w*256, w*256+256). Top-k phase: wave w owns queries w*2, w*2+1, merged in one
// interleaved loop (2 independent latency chains); pops prefetched off the
// critical path (all lanes speculatively load their next sorted element).
__global__ __launch_bounds__(512) void attn_mfma_topk(
    const u16* __restrict__ qb16, const u16* __restrict__ kb16,
    const float* __restrict__ vb, u16* __restrict__ aob16){
  __shared__ u16 sc_lds[16][2048];   // 64 KB
  int tid  = threadIdx.x;
  int w    = tid >> 6, l = tid & 63;
  int quad = l >> 4,  m = l & 15;
  int bh = blockIdx.y;
  int q0 = blockIdx.x * 16;

  const u16* Qp = qb16 + ((size_t)bh*2048 + q0 + m)*64 + quad*8;
  short8 a0 = *(const short8*)Qp;
  short8 a1 = *(const short8*)(Qp + 32);

  const u16* Kbase = kb16 + (size_t)bh*2048*64;
  for (int kt = 0; kt < 16; ++kt){
    int k0 = w*256 + kt*16;
    const u16* Kp = Kbase + (size_t)(k0 + m)*64 + quad*8;
    short8 b0 = *(const short8*)Kp;
    short8 b1 = *(const short8*)(Kp + 32);
    float4v acc = {0.f, 0.f, 0.f, 0.f};
    acc = __builtin_amdgcn_mfma_f32_16x16x32_bf16(a0, b0, acc, 0, 0, 0);
    acc = __builtin_amdgcn_mfma_f32_16x16x32_bf16(a1, b1, acc, 0, 0, 0);
    // C layout: row(query) = quad*4+r, col(key) = lane&15
    #pragma unroll
    for (int r = 0; r < 4; ++r)
      sc_lds[quad*4 + r][k0 + m] = f2b(acc[r] * 0.125f);
  }
  __syncthreads();

  int qA = w*2, qB = w*2 + 1;    // rows owned by this wave from here on
  u16* rowA = &sc_lds[qA][0];
  u16* rowB = &sc_lds[qB][0];

  // ---- load + per-lane bitonic sort (descending) + write back, per query ----
  float scA[32], scB[32];
  #pragma unroll
  for (int which = 0; which < 2; ++which){
    float* sc = which ? scB : scA;
    const uint2* p2 = (const uint2*)(which ? rowB : rowA);
    #pragma unroll
    for (int j = 0; j < 8; ++j){
      uint2 v2 = p2[j*64 + l];
      sc[j*4+0] = __uint_as_float(v2.x << 16);
      sc[j*4+1] = __uint_as_float(v2.x & 0xffff0000u);
      sc[j*4+2] = __uint_as_float(v2.y << 16);
      sc[j*4+3] = __uint_as_float(v2.y & 0xffff0000u);
    }
    #pragma unroll
    for (int k = 2; k <= 32; k <<= 1){
      #pragma unroll
      for (int j = k >> 1; j > 0; j >>= 1){
        #pragma unroll
        for (int i = 0; i < 32; ++i){
          int ixj = i ^ j;
          if (ixj > i){
            float a = sc[i], bb = sc[ixj];
            float hi = fmaxf(a, bb), lo = fminf(a, bb);
            if ((i & k) == 0){ sc[i] = hi; sc[ixj] = lo; }
            else             { sc[i] = lo; sc[ixj] = hi; }
          }
        }
      }
    }
    u16* row = which ? rowB : rowA;
    #pragma unroll
    for (int i = 0; i < 32; ++i) row[i*64 + l] = (u16)(__float_as_uint(sc[i]) >> 16);
  }

  // ---- interleaved 35-round rank merge for both queries ----
  float headA = scA[0], headB = scB[0];
  int   pA = 0, pB = 0;
  float nxtA = b2f16(rowA[64 + l]);
  float nxtB = b2f16(rowB[64 + l]);
  float tvA[TOPK], tvB[TOPK];
  #pragma unroll
  for (int r = 0; r < TOPK; ++r){
    float mA = headA, mB = headB;
    #pragma unroll
    for (int off = 32; off > 0; off >>= 1){
      mA = fmaxf(mA, __shfl_xor(mA, off, 64));
      mB = fmaxf(mB, __shfl_xor(mB, off, 64));
    }
    tvA[r] = mA;  tvB[r] = mB;
    unsigned long long mskA = __ballot(headA == mA);
    if (l == __ffsll(mskA) - 1){ headA = nxtA; ++pA; }
    unsigned long long mskB = __ballot(headB == mB);
    if (l == __ffsll(mskB) - 1){ headB = nxtB; ++pB; }
    // speculative prefetch of each lane's own next element (off critical path)
    nxtA = (pA + 1 < 32) ? b2f16(rowA[(pA + 1)*64 + l]) : -INFINITY;
    nxtB = (pB + 1 < 32) ? b2f16(rowB[(pB + 1)*64 + l]) : -INFINITY;
  }

  // ---- softmax + P@V[:35] for both queries (weight r pairs with V row r) ----
  const float* Vb = vb + (size_t)bh*2048*64 + l;   // lane = d
  int b = bh >> 3, hh = bh & 7;
  #pragma unroll
  for (int which = 0; which < 2; ++which){
    float* tv = which ? tvB : tvA;
    int q = which ? qB : qA;
    float mx = tv[0], denom = 0.f;
    #pragma unroll
    for (int r = 0; r < TOPK; ++r){ tv[r] = expf(tv[r] - mx); denom += tv[r]; }
    float inv = 1.f / denom;
    float acc = 0.f;
    #pragma unroll
    for (int r = 0; r < TOPK; ++r) acc += tv[r] * Vb[(size_t)r*64];
    acc *= inv;
    int s = q0 + q;
    aob16[(((size_t)(b*2048 + s))*8 + hh)*64 + l] = f2b(acc);
  }
}

// ---------------- h = LayerNorm(h + t) * g + b, in place; also bf16 copy ----------------
__global__ void resid_ln_kernel(float* __restrict__ h, const float* __restrict__ t,
                                const float* __restrict__ g, const float* __restrict__ b,
                                u16* __restrict__ h16){
  int tok = blockIdx.x;
  int tid = threadIdx.x;        // 256 threads, 2 elems each
  size_t base = (size_t)tok * 512;
  float x0 = h[base + tid]       + t[base + tid];
  float x1 = h[base + tid + 256] + t[base + tid + 256];
  __shared__ float red[8];
  int wid = tid >> 6, lane = tid & 63;

  float s = x0 + x1;
  #pragma unroll
  for (int off = 32; off > 0; off >>= 1) s += __shfl_xor(s, off, 64);
  if (lane == 0) red[wid] = s;
  __syncthreads();
  float mean = (red[0] + red[1] + red[2] + red[3]) * (1.f/512.f);

  float d0 = x0 - mean, d1 = x1 - mean;
  float sq = d0*d0 + d1*d1;
  #pragma unroll
  for (int off = 32; off > 0; off >>= 1) sq += __shfl_xor(sq, off, 64);
  if (lane == 0) red[4 + wid] = sq;
  __syncthreads();
  float var = (red[4] + red[5] + red[6] + red[7]) * (1.f/512.f);
  float inv = rsqrtf(var + 1e-5f);
  float o0 = d0 * inv * g[tid]       + b[tid];
  float o1 = d1 * inv * g[tid + 256] + b[tid + 256];
  h[base + tid]         = o0;  h16[base + tid]       = f2b(o0);
  h[base + tid + 256]   = o1;  h16[base + tid + 256] = f2b(o1);
}

// ---------------- mean over sequence ----------------
__global__ void pool_kernel(const float* __restrict__ h, float* __restrict__ pooled){
  int c = blockIdx.x * 256 + threadIdx.x;   // 0..511
  int b = blockIdx.y;
  const float* p = h + (size_t)b * 2048 * 512 + c;
  float acc = 0.f;
  for (int s = 0; s < 2048; ++s) acc += p[(size_t)s * 512];
  pooled[b*512 + c] = acc * (1.f/2048.f);
}

// ---------------- tiny decoder ----------------
__global__ void decoder_kernel(const float* __restrict__ pooled,
                               const float* __restrict__ w1, const float* __restrict__ b1,
                               const float* __restrict__ w2, const float* __restrict__ b2,
                               float* __restrict__ out){
  __shared__ float ps[4][512];
  __shared__ float hid[4][256];
  int tid = threadIdx.x;
  for (int i = tid; i < 2048; i += 256) ps[i >> 9][i & 511] = pooled[i];
  __syncthreads();
  float bb = b1[tid];
  for (int b = 0; b < 4; ++b){
    float acc = bb;
    for (int k = 0; k < 512; ++k) acc += ps[b][k] * w1[k*256 + tid];
    hid[b][tid] = fmaxf(acc, 0.f);
  }
  __syncthreads();
  if (tid < 8){
    int b = tid >> 1, c = tid & 1;
    float acc = b2[c];
    for (int j = 0; j < 256; ++j) acc += hid[b][j] * w2[j*2 + c];
    out[b*2 + c] = acc;
  }
}

extern "C" void kernel_launch(void* const* d_in, const int* in_sizes, int n_in,
                              void* d_out, int out_size, void* d_ws, size_t ws_size,
                              hipStream_t stream){
  const float* x     = (const float*)d_in[0];
  const float* emb_w = (const float*)d_in[1];
  const float* emb_b = (const float*)d_in[2];
  const float* wq    = (const float*)d_in[3];
  const float* bq    = (const float*)d_in[4];
  const float* wk    = (const float*)d_in[5];
  const float* bk    = (const float*)d_in[6];
  const float* wv    = (const float*)d_in[7];
  const float* bv    = (const float*)d_in[8];
  const float* wo    = (const float*)d_in[9];
  const float* bo    = (const float*)d_in[10];
  const float* ff1w  = (const float*)d_in[11];
  const float* ff1b  = (const float*)d_in[12];
  const float* ff2w  = (const float*)d_in[13];
  const float* ff2b  = (const float*)d_in[14];
  const float* ln1g  = (const float*)d_in[15];
  const float* ln1b  = (const float*)d_in[16];
  const float* ln2g  = (const float*)d_in[17];
  const float* ln2b  = (const float*)d_in[18];
  const float* d1w   = (const float*)d_in[19];
  const float* d1b   = (const float*)d_in[20];
  const float* d2w   = (const float*)d_in[21];
  const float* d2b   = (const float*)d_in[22];

  // ---- workspace layout (~92 MB) ----
  float* h      = (float*)d_ws;
  float* tmp    = h + NT512;
  u16*   u      = (u16*)(tmp + NT512);
  u16*   h16    = u;
  u16*   q16    = u + NT512;
  u16*   k16    = u + 2*NT512;
  float* vb     = (float*)(u + 3*NT512);
  u16*   ff16   = q16;
  u16*   aob16  = (u16*)(vb + NT512);
  u16*   wt     = aob16 + NT512;
  u16*   wt_qkv = wt;                          // 2 x 1536*512
  u16*   wt_wo  = wt_qkv + (size_t)2*1536*512; // 2 x 512*512
  u16*   wt_ff1 = wt_wo  + (size_t)2*512*512;  // 2 x 2048*512
  u16*   wt_ff2 = wt_ff1 + (size_t)2*2048*512; // 2 x 512*2048
  float* pooled = (float*)(wt_ff2 + (size_t)2*512*2048);

  dim3 tblk(32, 8);
  for (int l = 0; l < 2; ++l){
    convert_wt<<<dim3(16, 16), tblk, 0, stream>>>(wq + (size_t)l*512*512, wt_qkv + (size_t)l*1536*512,            512, 512);
    convert_wt<<<dim3(16, 16), tblk, 0, stream>>>(wk + (size_t)l*512*512, wt_qkv + (size_t)l*1536*512 + 512*512,  512, 512);
    convert_wt<<<dim3(16, 16), tblk, 0, stream>>>(wv + (size_t)l*512*512, wt_qkv + (size_t)l*1536*512 + 1024*512, 512, 512);
    convert_wt<<<dim3(16, 16), tblk, 0, stream>>>(wo + (size_t)l*512*512, wt_wo + (size_t)l*512*512, 512, 512);
    convert_wt<<<dim3(64, 16), tblk, 0, stream>>>(ff1w + (size_t)l*512*2048, wt_ff1 + (size_t)l*2048*512, 512, 2048);
    convert_wt<<<dim3(16, 64), tblk, 0, stream>>>(ff2w + (size_t)l*2048*512, wt_ff2 + (size_t)l*512*2048, 2048, 512);
  }

  embed_kernel<<<NTOK, 256, 0, stream>>>(x, emb_w, emb_b, h, h16);

  for (int l = 0; l < 2; ++l){
    gemm_mfma<2><<<dim3(12, 64), 256, 0, stream>>>(
        h16, wt_qkv + (size_t)l*1536*512,
        bq + l*512, bk + l*512, bv + l*512,
        nullptr, q16, k16, vb, NTOK, 1536, 512);

    attn_mfma_topk<<<dim3(128, 32), 512, 0, stream>>>(q16, k16, vb, aob16);

    gemm_mfma<0><<<dim3(4, 64), 256, 0, stream>>>(
        aob16, wt_wo + (size_t)l*512*512, bo + l*512, nullptr, nullptr,
        tmp, nullptr, nullptr, nullptr, NTOK, 512, 512);
    resid_ln_kernel<<<NTOK, 256, 0, stream>>>(h, tmp, ln1g + l*512, ln1b + l*512, h16);

    gemm_mfma<1><<<dim3(16, 64), 256, 0, stream>>>(
        h16, wt_ff1 + (size_t)l*2048*512, ff1b + l*2048, nullptr, nullptr,
        nullptr, ff16, nullptr, nullptr, NTOK, 2048, 512);
    gemm_mfma<0><<<dim3(4, 64), 256, 0, stream>>>(
        ff16, wt_ff2 + (size_t)l*512*2048, ff2b + l*512, nullptr, nullptr,
        tmp, nullptr, nullptr, nullptr, NTOK, 512, 2048);
    resid_ln_kernel<<<NTOK, 256, 0, stream>>>(h, tmp, ln2g + l*512, ln2b + l*512, h16);
  }

  pool_kernel<<<dim3(2, 4), 256, 0, stream>>>(h, pooled);
  decoder_kernel<<<1, 256, 0, stream>>>(pooled, d1w, d1b, d2w, d2b, (float*)d_out);
}

// Round 7
// 965.945 us; speedup vs baseline: 13.1191x; 1.1255x over previous
//
#include <hip/hip_runtime.h>
#include <cmath>

typedef unsigned short u16;
typedef __attribute__((ext_vector_type(8))) short short8;
typedef __attribute__((ext_vector_type(4))) float float4v;
typedef unsigned short ushort2v __attribute__((ext_vector_type(2)));

#define S_LEN 2048
#define NTOK  8192   // B*S
#define TOPK  35
#define NT512 ((size_t)NTOK*512)

__device__ __forceinline__ u16 f2b(float f){
  unsigned int x = __float_as_uint(f);
  unsigned int r = (x + 0x7fffu + ((x >> 16) & 1u)) >> 16;
  return (u16)r;
}

// bf16(f) -> monotone-increasing u16 sort key (no NaNs assumed)
__device__ __forceinline__ unsigned key_of(float f){
  unsigned u = (unsigned)f2b(f);
  unsigned m = (u & 0x8000u) ? 0xFFFFu : 0x8000u;
  return (u ^ m) & 0xFFFFu;
}
// key -> float (bf16 value)
__device__ __forceinline__ float key_to_f(unsigned key){
  unsigned m = (key & 0x8000u) ? 0x8000u : 0xFFFFu;
  return __uint_as_float(((key ^ m) & 0xFFFFu) << 16);
}
// packed 2x u16 max/min (v_pk_max_u16 / v_pk_min_u16)
__device__ __forceinline__ unsigned pkmax(unsigned a, unsigned b){
  union { unsigned u; ushort2v v; } x, y, r;
  x.u = a; y.u = b;
  r.v = __builtin_elementwise_max(x.v, y.v);
  return r.u;
}
__device__ __forceinline__ unsigned pkmin(unsigned a, unsigned b){
  union { unsigned u; ushort2v v; } x, y, r;
  x.u = a; y.u = b;
  r.v = __builtin_elementwise_min(x.v, y.v);
  return r.u;
}

// ---------------- weight transpose + bf16 convert: Wt[n][k] = bf16(W[k][n]) ----------------
__global__ void convert_wt(const float* __restrict__ W, u16* __restrict__ Wt, int K, int N){
  __shared__ u16 t[32][33];
  int k0 = blockIdx.y*32, n0 = blockIdx.x*32;
  int tx = threadIdx.x, ty = threadIdx.y;   // 32x8
  #pragma unroll
  for (int i = ty; i < 32; i += 8)
    t[i][tx] = f2b(W[(size_t)(k0+i)*N + n0+tx]);
  __syncthreads();
  #pragma unroll
  for (int i = ty; i < 32; i += 8)
    Wt[(size_t)(n0+i)*K + k0+tx] = t[tx][i];
}

// ---------------- embedding + sinusoidal PE (writes fp32 h + bf16 h16) ----------------
__global__ void embed_kernel(const float* __restrict__ x, const float* __restrict__ w,
                             const float* __restrict__ bias, float* __restrict__ h,
                             u16* __restrict__ h16){
  int t = blockIdx.x;          // token 0..8191
  int tid = threadIdx.x;       // 0..255
  __shared__ float xs[64];
  if (tid < 64) xs[tid] = x[(size_t)t*64 + tid];
  __syncthreads();
  float acc0 = bias[tid];
  float acc1 = bias[tid + 256];
  #pragma unroll 8
  for (int k = 0; k < 64; ++k){
    float xv = xs[k];
    acc0 += xv * w[k*512 + tid];
    acc1 += xv * w[k*512 + tid + 256];
  }
  int s = t & (S_LEN - 1);
  const float neg_ln1e4_over_D = -9.210340371976184f / 512.f;
  int c0 = tid, c1 = tid + 256;
  float a0 = (float)s * expf((float)(c0 & ~1) * neg_ln1e4_over_D);
  float p0 = (c0 & 1) ? cosf(a0) : sinf(a0);
  float a1 = (float)s * expf((float)(c1 & ~1) * neg_ln1e4_over_D);
  float p1 = (c1 & 1) ? cosf(a1) : sinf(a1);
  float v0 = acc0 + p0, v1 = acc1 + p1;
  h[(size_t)t*512 + c0] = v0;  h16[(size_t)t*512 + c0] = f2b(v0);
  h[(size_t)t*512 + c1] = v1;  h16[(size_t)t*512 + c1] = f2b(v1);
}

// ---------------- bf16 MFMA GEMM: C = A[M,K](bf16) @ Bt[N,K]^T(bf16) + bias ----------------
template<int EPI>
__global__ __launch_bounds__(256) void gemm_mfma(
    const u16* __restrict__ A, const u16* __restrict__ Bt,
    const float* __restrict__ bias0, const float* __restrict__ bias1,
    const float* __restrict__ bias2,
    float* __restrict__ Cf, u16* __restrict__ C16a, u16* __restrict__ C16b,
    float* __restrict__ Cv, int M, int N, int K){
  __shared__ __align__(16) u16 As[128*64];
  __shared__ __align__(16) u16 Bs[128*64];
  int tid = threadIdx.x;
  int w = tid >> 6, l = tid & 63, quad = l >> 4, m = l & 15;
  int m0 = blockIdx.y*128, n0 = blockIdx.x*128;
  int mh = (w >> 1)*64, nh = (w & 1)*64;
  float4v acc[4][4];
  #pragma unroll
  for (int i = 0; i < 4; ++i)
    #pragma unroll
    for (int j = 0; j < 4; ++j) acc[i][j] = (float4v){0.f,0.f,0.f,0.f};

  for (int kt = 0; kt < K; kt += 64){
    #pragma unroll
    for (int c = 0; c < 4; ++c){
      int g = c*256 + tid;
      int row = g >> 3, sc = g & 7, dc = sc ^ (row & 7);
      uint4 av = *(const uint4*)(A  + (size_t)(m0+row)*K + kt + dc*8);
      uint4 bv = *(const uint4*)(Bt + (size_t)(n0+row)*K + kt + dc*8);
      *(uint4*)(As + (size_t)g*8) = av;
      *(uint4*)(Bs + (size_t)g*8) = bv;
    }
    __syncthreads();
    #pragma unroll
    for (int kk = 0; kk < 2; ++kk){
      short8 af[4], bf[4];
      #pragma unroll
      for (int i = 0; i < 4; ++i){
        int dcx = kk*4 + quad;
        int ra = mh + i*16 + m;
        af[i] = *(const short8*)(As + (size_t)(ra*8 + (dcx ^ (ra & 7)))*8);
        int rb = nh + i*16 + m;
        bf[i] = *(const short8*)(Bs + (size_t)(rb*8 + (dcx ^ (rb & 7)))*8);
      }
      #pragma unroll
      for (int i = 0; i < 4; ++i)
        #pragma unroll
        for (int j = 0; j < 4; ++j)
          acc[i][j] = __builtin_amdgcn_mfma_f32_16x16x32_bf16(af[i], bf[j], acc[i][j], 0, 0, 0);
    }
    __syncthreads();
  }

  // C/D layout: row_local = quad*4+r, col_local = m
  #pragma unroll
  for (int i = 0; i < 4; ++i){
    #pragma unroll
    for (int j = 0; j < 4; ++j){
      int col = n0 + nh + j*16 + m;
      #pragma unroll
      for (int r = 0; r < 4; ++r){
        int row = m0 + mh + i*16 + quad*4 + r;
        float v = acc[i][j][r];
        if (EPI == 0){
          Cf[(size_t)row*N + col] = v + bias0[col];
        } else if (EPI == 1){
          C16a[(size_t)row*N + col] = f2b(fmaxf(v + bias0[col], 0.f));
        } else {
          int sel = col >> 9, n5 = col & 511;
          const float* bp = (sel == 0) ? bias0 : (sel == 1) ? bias1 : bias2;
          float vv = v + bp[n5];
          int d = n5 & 63, hh = n5 >> 6;
          int b = row >> 11, s = row & 2047;
          size_t idx = (((size_t)(b*8 + hh))*2048 + s)*64 + d;
          if (sel == 0)      C16a[idx] = f2b(vv);
          else if (sel == 1) C16b[idx] = f2b(vv);
          else               Cv[idx]  = vv;
        }
      }
    }
  }
}

// ---------------- fused MFMA scores + top-35 + softmax + P@V[:35] ----------------
// 512 thr (8 waves) per (bh, 16-query tile). Scores stored as PACKED u16 sort
// keys: pair-row P (u32 [8][2048]) holds (key(query 2P+1)<<16)|key(query 2P).
// Wave w owns pair-row w: packed bitonic sort (v_pk_max/min_u16 sorts both
// query lists at once), packed 6-shuffle merge reduce, per-half pops.
__global__ __launch_bounds__(512) void attn_mfma_topk(
    const u16* __restrict__ qb16, const u16* __restrict__ kb16,
    const float* __restrict__ vb, u16* __restrict__ aob16){
  __shared__ unsigned pr[8*2048];   // 64 KB
  int tid  = threadIdx.x;
  int w    = tid >> 6, l = tid & 63;
  int quad = l >> 4,  m = l & 15;
  int bh = blockIdx.y;
  int q0 = blockIdx.x * 16;

  const u16* Qp = qb16 + ((size_t)bh*2048 + q0 + m)*64 + quad*8;
  short8 a0 = *(const short8*)Qp;
  short8 a1 = *(const short8*)(Qp + 32);

  const u16* Kbase = kb16 + (size_t)bh*2048*64;
  for (int kt = 0; kt < 16; ++kt){
    int k0 = w*256 + kt*16;
    const u16* Kp = Kbase + (size_t)(k0 + m)*64 + quad*8;
    short8 b0 = *(const short8*)Kp;
    short8 b1 = *(const short8*)(Kp + 32);
    float4v acc = {0.f, 0.f, 0.f, 0.f};
    acc = __builtin_amdgcn_mfma_f32_16x16x32_bf16(a0, b0, acc, 0, 0, 0);
    acc = __builtin_amdgcn_mfma_f32_16x16x32_bf16(a1, b1, acc, 0, 0, 0);
    // C layout: row(query)=quad*4+r, col(key)=m. Pack rows (2c,2c+1) -> pair row quad*2+c.
    #pragma unroll
    for (int c = 0; c < 2; ++c){
      unsigned lo = key_of(acc[2*c]);
      unsigned hi = key_of(acc[2*c+1]);
      pr[(quad*2 + c)*2048 + k0 + m] = lo | (hi << 16);
    }
  }
  __syncthreads();

  unsigned* row = &pr[w*2048];   // pair row w: queries 2w, 2w+1 (wave-private now)

  // ---- load 32 packed elems (contiguous b128 reads) ----
  unsigned sc[32];
  const uint4* p4 = (const uint4*)row;
  #pragma unroll
  for (int j = 0; j < 8; ++j){
    uint4 v4 = p4[j*64 + l];
    sc[j*4+0] = v4.x; sc[j*4+1] = v4.y; sc[j*4+2] = v4.z; sc[j*4+3] = v4.w;
  }

  // ---- packed bitonic sort, descending (both query lists at once) ----
  #pragma unroll
  for (int k = 2; k <= 32; k <<= 1){
    #pragma unroll
    for (int j = k >> 1; j > 0; j >>= 1){
      #pragma unroll
      for (int i = 0; i < 32; ++i){
        int ixj = i ^ j;
        if (ixj > i){
          unsigned a = sc[i], b = sc[ixj];
          unsigned hi = pkmax(a, b), lo = pkmin(a, b);
          if ((i & k) == 0){ sc[i] = hi; sc[ixj] = lo; }
          else             { sc[i] = lo; sc[ixj] = hi; }
        }
      }
    }
  }

  // writeback sorted: element i at row[i*64 + l] (2-way bank = free)
  #pragma unroll
  for (int i = 0; i < 32; ++i) row[i*64 + l] = sc[i];

  // ---- 35-round packed rank merge ----
  unsigned headA = sc[0] & 0xFFFFu, headB = sc[0] >> 16;
  unsigned nxtA  = sc[1] & 0xFFFFu, nxtB  = sc[1] >> 16;
  int pA = 0, pB = 0;
  unsigned tvP[TOPK];
  #pragma unroll
  for (int r = 0; r < TOPK; ++r){
    unsigned mP = headA | (headB << 16);
    #pragma unroll
    for (int off = 32; off > 0; off >>= 1)
      mP = pkmax(mP, __shfl_xor(mP, off, 64));
    tvP[r] = mP;
    unsigned mA = mP & 0xFFFFu, mB = mP >> 16;
    unsigned long long bA = __ballot(headA == mA);
    if (l == __ffsll(bA) - 1){ headA = nxtA; ++pA; }
    unsigned long long bB = __ballot(headB == mB);
    if (l == __ffsll(bB) - 1){ headB = nxtB; ++pB; }
    // speculative prefetch of each lane's own next element (off critical path)
    nxtA = (pA + 1 < 32) ? (row[(pA + 1)*64 + l] & 0xFFFFu) : 0u;
    nxtB = (pB + 1 < 32) ? (row[(pB + 1)*64 + l] >> 16)     : 0u;
  }

  // ---- softmax + P@V[:35] for both queries (weight r pairs with V row r) ----
  const float* Vb = vb + (size_t)bh*2048*64 + l;   // lane = d
  float vreg[TOPK];
  #pragma unroll
  for (int r = 0; r < TOPK; ++r) vreg[r] = Vb[(size_t)r*64];
  int b = bh >> 3, hh = bh & 7;
  #pragma unroll
  for (int which = 0; which < 2; ++which){
    float tv[TOPK];
    #pragma unroll
    for (int r = 0; r < TOPK; ++r){
      unsigned key = which ? (tvP[r] >> 16) : (tvP[r] & 0xFFFFu);
      tv[r] = key_to_f(key) * 0.125f;
    }
    float mx = tv[0], denom = 0.f, acc = 0.f;
    #pragma unroll
    for (int r = 0; r < TOPK; ++r){
      float e = __expf(tv[r] - mx);
      denom += e;
      acc += e * vreg[r];
    }
    acc /= denom;
    int s = q0 + w*2 + which;
    aob16[(((size_t)(b*2048 + s))*8 + hh)*64 + l] = f2b(acc);
  }
}

// ---------------- h = LayerNorm(h + t) * g + b, in place; also bf16 copy ----------------
__global__ void resid_ln_kernel(float* __restrict__ h, const float* __restrict__ t,
                                const float* __restrict__ g, const float* __restrict__ b,
                                u16* __restrict__ h16){
  int tok = blockIdx.x;
  int tid = threadIdx.x;        // 256 threads, 2 elems each
  size_t base = (size_t)tok * 512;
  float x0 = h[base + tid]       + t[base + tid];
  float x1 = h[base + tid + 256] + t[base + tid + 256];
  __shared__ float red[8];
  int wid = tid >> 6, lane = tid & 63;

  float s = x0 + x1;
  #pragma unroll
  for (int off = 32; off > 0; off >>= 1) s += __shfl_xor(s, off, 64);
  if (lane == 0) red[wid] = s;
  __syncthreads();
  float mean = (red[0] + red[1] + red[2] + red[3]) * (1.f/512.f);

  float d0 = x0 - mean, d1 = x1 - mean;
  float sq = d0*d0 + d1*d1;
  #pragma unroll
  for (int off = 32; off > 0; off >>= 1) sq += __shfl_xor(sq, off, 64);
  if (lane == 0) red[4 + wid] = sq;
  __syncthreads();
  float var = (red[4] + red[5] + red[6] + red[7]) * (1.f/512.f);
  float inv = rsqrtf(var + 1e-5f);
  float o0 = d0 * inv * g[tid]       + b[tid];
  float o1 = d1 * inv * g[tid + 256] + b[tid + 256];
  h[base + tid]         = o0;  h16[base + tid]       = f2b(o0);
  h[base + tid + 256]   = o1;  h16[base + tid + 256] = f2b(o1);
}

// ---------------- mean over sequence ----------------
__global__ void pool_kernel(const float* __restrict__ h, float* __restrict__ pooled){
  int c = blockIdx.x * 256 + threadIdx.x;   // 0..511
  int b = blockIdx.y;
  const float* p = h + (size_t)b * 2048 * 512 + c;
  float acc = 0.f;
  for (int s = 0; s < 2048; ++s) acc += p[(size_t)s * 512];
  pooled[b*512 + c] = acc * (1.f/2048.f);
}

// ---------------- tiny decoder ----------------
__global__ void decoder_kernel(const float* __restrict__ pooled,
                               const float* __restrict__ w1, const float* __restrict__ b1,
                               const float* __restrict__ w2, const float* __restrict__ b2,
                               float* __restrict__ out){
  __shared__ float ps[4][512];
  __shared__ float hid[4][256];
  int tid = threadIdx.x;
  for (int i = tid; i < 2048; i += 256) ps[i >> 9][i & 511] = pooled[i];
  __syncthreads();
  float bb = b1[tid];
  for (int b = 0; b < 4; ++b){
    float acc = bb;
    for (int k = 0; k < 512; ++k) acc += ps[b][k] * w1[k*256 + tid];
    hid[b][tid] = fmaxf(acc, 0.f);
  }
  __syncthreads();
  if (tid < 8){
    int b = tid >> 1, c = tid & 1;
    float acc = b2[c];
    for (int j = 0; j < 256; ++j) acc += hid[b][j] * w2[j*2 + c];
    out[b*2 + c] = acc;
  }
}

extern "C" void kernel_launch(void* const* d_in, const int* in_sizes, int n_in,
                              void* d_out, int out_size, void* d_ws, size_t ws_size,
                              hipStream_t stream){
  const float* x     = (const float*)d_in[0];
  const float* emb_w = (const float*)d_in[1];
  const float* emb_b = (const float*)d_in[2];
  const float* wq    = (const float*)d_in[3];
  const float* bq    = (const float*)d_in[4];
  const float* wk    = (const float*)d_in[5];
  const float* bk    = (const float*)d_in[6];
  const float* wv    = (const float*)d_in[7];
  const float* bv    = (const float*)d_in[8];
  const float* wo    = (const float*)d_in[9];
  const float* bo    = (const float*)d_in[10];
  const float* ff1w  = (const float*)d_in[11];
  const float* ff1b  = (const float*)d_in[12];
  const float* ff2w  = (const float*)d_in[13];
  const float* ff2b  = (const float*)d_in[14];
  const float* ln1g  = (const float*)d_in[15];
  const float* ln1b  = (const float*)d_in[16];
  const float* ln2g  = (const float*)d_in[17];
  const float* ln2b  = (const float*)d_in[18];
  const float* d1w   = (const float*)d_in[19];
  const float* d1b   = (const float*)d_in[20];
  const float* d2w   = (const float*)d_in[21];
  const float* d2b   = (const float*)d_in[22];

  // ---- workspace layout (~92 MB) ----
  float* h      = (float*)d_ws;
  float* tmp    = h + NT512;
  u16*   u      = (u16*)(tmp + NT512);
  u16*   h16    = u;
  u16*   q16    = u + NT512;
  u16*   k16    = u + 2*NT512;
  float* vb     = (float*)(u + 3*NT512);
  u16*   ff16   = q16;
  u16*   aob16  = (u16*)(vb + NT512);
  u16*   wt     = aob16 + NT512;
  u16*   wt_qkv = wt;                          // 2 x 1536*512
  u16*   wt_wo  = wt_qkv + (size_t)2*1536*512; // 2 x 512*512
  u16*   wt_ff1 = wt_wo  + (size_t)2*512*512;  // 2 x 2048*512
  u16*   wt_ff2 = wt_ff1 + (size_t)2*2048*512; // 2 x 512*2048
  float* pooled = (float*)(wt_ff2 + (size_t)2*512*2048);

  dim3 tblk(32, 8);
  for (int l = 0; l < 2; ++l){
    convert_wt<<<dim3(16, 16), tblk, 0, stream>>>(wq + (size_t)l*512*512, wt_qkv + (size_t)l*1536*512,            512, 512);
    convert_wt<<<dim3(16, 16), tblk, 0, stream>>>(wk + (size_t)l*512*512, wt_qkv + (size_t)l*1536*512 + 512*512,  512, 512);
    convert_wt<<<dim3(16, 16), tblk, 0, stream>>>(wv + (size_t)l*512*512, wt_qkv + (size_t)l*1536*512 + 1024*512, 512, 512);
    convert_wt<<<dim3(16, 16), tblk, 0, stream>>>(wo + (size_t)l*512*512, wt_wo + (size_t)l*512*512, 512, 512);
    convert_wt<<<dim3(64, 16), tblk, 0, stream>>>(ff1w + (size_t)l*512*2048, wt_ff1 + (size_t)l*2048*512, 512, 2048);
    convert_wt<<<dim3(16, 64), tblk, 0, stream>>>(ff2w + (size_t)l*2048*512, wt_ff2 + (size_t)l*512*2048, 2048, 512);
  }

  embed_kernel<<<NTOK, 256, 0, stream>>>(x, emb_w, emb_b, h, h16);

  for (int l = 0; l < 2; ++l){
    gemm_mfma<2><<<dim3(12, 64), 256, 0, stream>>>(
        h16, wt_qkv + (size_t)l*1536*512,
        bq + l*512, bk + l*512, bv + l*512,
        nullptr, q16, k16, vb, NTOK, 1536, 512);

    attn_mfma_topk<<<dim3(128, 32), 512, 0, stream>>>(q16, k16, vb, aob16);

    gemm_mfma<0><<<dim3(4, 64), 256, 0, stream>>>(
        aob16, wt_wo + (size_t)l*512*512, bo + l*512, nullptr, nullptr,
        tmp, nullptr, nullptr, nullptr, NTOK, 512, 512);
    resid_ln_kernel<<<NTOK, 256, 0, stream>>>(h, tmp, ln1g + l*512, ln1b + l*512, h16);

    gemm_mfma<1><<<dim3(16, 64), 256, 0, stream>>>(
        h16, wt_ff1 + (size_t)l*2048*512, ff1b + l*2048, nullptr, nullptr,
        nullptr, ff16, nullptr, nullptr, NTOK, 2048, 512);
    gemm_mfma<0><<<dim3(4, 64), 256, 0, stream>>>(
        ff16, wt_ff2 + (size_t)l*512*2048, ff2b + l*512, nullptr, nullptr,
        tmp, nullptr, nullptr, nullptr, NTOK, 512, 2048);
    resid_ln_kernel<<<NTOK, 256, 0, stream>>>(h, tmp, ln2g + l*512, ln2b + l*512, h16);
  }

  pool_kernel<<<dim3(2, 4), 256, 0, stream>>>(h, pooled);
  decoder_kernel<<<1, 256, 0, stream>>>(pooled, d1w, d1b, d2w, d2b, (float*)d_out);
}